// Round 3
// baseline (1715.684 us; speedup 1.0000x reference)
//
#include <hip/hip_runtime.h>
#include <math.h>

#define N_POS 100352   // 8*112*112
#define HW    12544    // 112*112

__device__ __forceinline__ void fma4(float4& c, float s, const float4 w){
  c.x = fmaf(s, w.x, c.x); c.y = fmaf(s, w.y, c.y);
  c.z = fmaf(s, w.z, c.z); c.w = fmaf(s, w.w, c.w);
}

// ---------------- zero ----------------
__global__ void zero_kernel(float* p, int n){
  int i = blockIdx.x*256 + threadIdx.x;
  if (i < n) p[i] = 0.f;
}

// ---------------- LayerNorm (128 ch), one wave per row ----------------
__global__ __launch_bounds__(256) void ln128_kernel(const float* __restrict__ in,
    const float* __restrict__ w, const float* __restrict__ b, float* __restrict__ out){
  int row  = blockIdx.x*4 + (threadIdx.x >> 6);
  int lane = threadIdx.x & 63;
  const float* p = in + (size_t)row*128;
  float2 v = *(const float2*)(p + lane*2);
  float s = v.x + v.y;
  #pragma unroll
  for (int o = 1; o < 64; o <<= 1) s += __shfl_xor(s, o);
  float mu = s * (1.0f/128.0f);
  float dx = v.x - mu, dy = v.y - mu;
  float q = dx*dx + dy*dy;
  #pragma unroll
  for (int o = 1; o < 64; o <<= 1) q += __shfl_xor(q, o);
  float rs = rsqrtf(q * (1.0f/128.0f) + 1e-6f);
  int c = lane*2;
  float2 o2;
  o2.x = dx*rs*w[c]   + b[c];
  o2.y = dy*rs*w[c+1] + b[c+1];
  *(float2*)(out + (size_t)row*128 + c) = o2;
}

// ---------------- LayerNorm (64 ch) ----------------
__global__ __launch_bounds__(256) void ln64_kernel(const float* __restrict__ in,
    const float* __restrict__ w, const float* __restrict__ b, float* __restrict__ out){
  int row  = blockIdx.x*4 + (threadIdx.x >> 6);
  int lane = threadIdx.x & 63;
  float v = in[(size_t)row*64 + lane];
  float s = v;
  #pragma unroll
  for (int o = 1; o < 64; o <<= 1) s += __shfl_xor(s, o);
  float mu = s * (1.0f/64.0f);
  float d = v - mu;
  float q = d*d;
  #pragma unroll
  for (int o = 1; o < 64; o <<= 1) q += __shfl_xor(q, o);
  float rs = rsqrtf(q * (1.0f/64.0f) + 1e-6f);
  out[(size_t)row*64 + lane] = d*rs*w[lane] + b[lane];
}

// ---------------- generic tiled fp32 GEMM ----------------
// out = [A (optionally col-scaled per batch) @ W + bias] (optionally * mult)
struct ColTile {
  const float* W; const float* bias; float* out; const float* mult;
  int ldw; int ldo; int ldm;
};
struct GemmParams {
  const float* A; const float* scale;  // scale: [B][K] applied to A cols (may be null)
  int lda; int K; int rowsPerB;
  ColTile tiles[8];
};

__global__ __launch_bounds__(256,2) void gemm_tiled(GemmParams p){
  __shared__ float As[64*68];   // [m][k] stride 68
  __shared__ float Ws[64*64];   // [k][n]
  const int tid = threadIdx.x;
  const int tx = tid & 15, ty = tid >> 4;
  const int kk = tx*4;
  const int row0 = blockIdx.x * 64;
  ColTile tile = p.tiles[blockIdx.y];
  float4 acc0 = make_float4(0,0,0,0), acc1 = acc0, acc2 = acc0, acc3 = acc0;
  const float* scale = p.scale ? (p.scale + (size_t)(row0 / p.rowsPerB) * p.K) : (const float*)0;

  for (int k0 = 0; k0 < p.K; k0 += 64) {
    #pragma unroll
    for (int m = ty; m < 64; m += 16) {
      float4 a = *(const float4*)(p.A + (size_t)(row0+m)*p.lda + k0 + kk);
      if (scale) {
        a.x *= scale[k0+kk]; a.y *= scale[k0+kk+1];
        a.z *= scale[k0+kk+2]; a.w *= scale[k0+kk+3];
      }
      *(float4*)&As[m*68 + kk] = a;
    }
    #pragma unroll
    for (int k = ty; k < 64; k += 16)
      *(float4*)&Ws[k*64 + kk] = *(const float4*)(tile.W + (size_t)(k0+k)*tile.ldw + kk);
    __syncthreads();
    #pragma unroll 4
    for (int k = 0; k < 64; k += 4) {
      float4 w0 = *(const float4*)&Ws[(k+0)*64 + kk];
      float4 w1 = *(const float4*)&Ws[(k+1)*64 + kk];
      float4 w2 = *(const float4*)&Ws[(k+2)*64 + kk];
      float4 w3 = *(const float4*)&Ws[(k+3)*64 + kk];
      float4 a0 = *(const float4*)&As[(ty*4+0)*68 + k];
      float4 a1 = *(const float4*)&As[(ty*4+1)*68 + k];
      float4 a2 = *(const float4*)&As[(ty*4+2)*68 + k];
      float4 a3 = *(const float4*)&As[(ty*4+3)*68 + k];
      fma4(acc0,a0.x,w0); fma4(acc0,a0.y,w1); fma4(acc0,a0.z,w2); fma4(acc0,a0.w,w3);
      fma4(acc1,a1.x,w0); fma4(acc1,a1.y,w1); fma4(acc1,a1.z,w2); fma4(acc1,a1.w,w3);
      fma4(acc2,a2.x,w0); fma4(acc2,a2.y,w1); fma4(acc2,a2.z,w2); fma4(acc2,a2.w,w3);
      fma4(acc3,a3.x,w0); fma4(acc3,a3.y,w1); fma4(acc3,a3.z,w2); fma4(acc3,a3.w,w3);
    }
    __syncthreads();
  }
  float4 bias = *(const float4*)(tile.bias + kk);
  float4 accs[4] = {acc0, acc1, acc2, acc3};
  #pragma unroll
  for (int i = 0; i < 4; i++) {
    int row = row0 + ty*4 + i;
    float4 o;
    o.x = accs[i].x + bias.x; o.y = accs[i].y + bias.y;
    o.z = accs[i].z + bias.z; o.w = accs[i].w + bias.w;
    if (tile.mult) {
      float4 mv = *(const float4*)(tile.mult + (size_t)row*tile.ldm + kk);
      o.x *= mv.x; o.y *= mv.y; o.z *= mv.z; o.w *= mv.w;
    }
    *(float4*)(tile.out + (size_t)row*tile.ldo + kk) = o;
  }
}

// ---------------- 7x7 depthwise conv, 128 channels ----------------
__global__ __launch_bounds__(256) void dwconv128_kernel(const float* __restrict__ in,
    const float* __restrict__ cw, const float* __restrict__ cb, float* __restrict__ out){
  __shared__ float wsm[128*49];
  int t = threadIdx.x;
  for (int i = t; i < 128*49; i += 256) wsm[i] = cw[i];
  __syncthreads();
  int c = t & 127;
  int r = blockIdx.x*2 + (t >> 7);
  int b = r / HW, rem = r % HW, y = rem / 112, x = rem % 112;
  float acc = cb[c];
  #pragma unroll
  for (int ky = 0; ky < 7; ky++) {
    int yy = y + ky - 3;
    if ((unsigned)yy >= 112u) continue;
    #pragma unroll
    for (int kx = 0; kx < 7; kx++) {
      int xx = x + kx - 3;
      if ((unsigned)xx >= 112u) continue;
      acc += wsm[c*49 + ky*7 + kx] * in[((size_t)(b*112+yy)*112 + xx)*128 + c];
    }
  }
  out[(size_t)r*128 + c] = acc;
}

// ---------------- co/di: dwconv(rgb*t) & dwconv(|rgb-t|), 64+64 ch ----------------
__global__ __launch_bounds__(256) void dwconv_codi_kernel(
    const float* __restrict__ rgb, const float* __restrict__ tb,
    const float* __restrict__ w1, const float* __restrict__ b1,
    const float* __restrict__ w2, const float* __restrict__ b2,
    float* __restrict__ out){
  __shared__ float wsm[2*64*49];
  int t = threadIdx.x;
  for (int i = t; i < 64*49; i += 256) { wsm[i] = w1[i]; wsm[3136+i] = w2[i]; }
  __syncthreads();
  int c = t & 127, cc = c & 63;
  bool isco = c < 64;
  int r = blockIdx.x*2 + (t >> 7);
  int b = r / HW, rem = r % HW, y = rem / 112, x = rem % 112;
  float acc = isco ? b1[cc] : b2[cc];
  const float* wp = wsm + (isco ? 0 : 3136) + cc*49;
  #pragma unroll
  for (int ky = 0; ky < 7; ky++) {
    int yy = y + ky - 3;
    if ((unsigned)yy >= 112u) continue;
    #pragma unroll
    for (int kx = 0; kx < 7; kx++) {
      int xx = x + kx - 3;
      if ((unsigned)xx >= 112u) continue;
      size_t pos = (size_t)(b*112+yy)*112 + xx;
      float a = rgb[pos*64 + cc], bv = tb[pos*64 + cc];
      float v = isco ? a*bv : fabsf(a - bv);
      acc += wp[ky*7 + kx] * v;
    }
  }
  out[(size_t)r*128 + c] = acc;
}

// ---------------- cosine-gate reductions ----------------
__global__ __launch_bounds__(256) void reduce_kernel(const float* __restrict__ codi,
    float* __restrict__ dotb, float* __restrict__ n1sq, float* __restrict__ n2sq){
  int blk = blockIdx.x;          // 392 = 8 b * 49 segs
  int b = blk / 49, seg = blk % 49;
  int lane = threadIdx.x & 63, w = threadIdx.x >> 6;
  int c = lane*2;
  float d0=0,d1=0,s0=0,s1=0,a1=0;
  for (int i = 0; i < 64; i++) {
    int row = b*HW + seg*256 + w*64 + i;
    float2 v = *(const float2*)(codi + (size_t)row*128 + c);
    float rs = v.x + v.y;
    #pragma unroll
    for (int o = 1; o < 64; o <<= 1) rs += __shfl_xor(rs, o);
    float amap = rs * (1.0f/128.0f);
    d0 += amap*v.x; d1 += amap*v.y;
    s0 += v.x*v.x;  s1 += v.y*v.y;
    if (lane == 0) a1 += amap*amap;
  }
  atomicAdd(&dotb[b*128+c],   d0); atomicAdd(&dotb[b*128+c+1], d1);
  atomicAdd(&n2sq[b*128+c],   s0); atomicAdd(&n2sq[b*128+c+1], s1);
  if (lane == 0) atomicAdd(&n1sq[b], a1);
}

__global__ __launch_bounds__(256) void attc_kernel(const float* __restrict__ dotb,
    const float* __restrict__ n1sq, const float* __restrict__ n2sq,
    const float* __restrict__ fc1, const float* __restrict__ fc2, float* __restrict__ attc){
  __shared__ float scos[128];
  __shared__ float sh[16];
  int t = threadIdx.x;
  for (int b = 0; b < 8; b++) {
    if (t < 128) {
      float n1 = sqrtf(n1sq[b]);
      float n2 = sqrtf(n2sq[b*128+t]);
      scos[t] = dotb[b*128+t] / (n1*n2 + 1e-6f);
    }
    __syncthreads();
    if (t < 16) {
      float h = 0;
      for (int c = 0; c < 128; c++) h += scos[c]*fc1[c*16+t];
      sh[t] = h * 0.5f * (1.0f + erff(h*0.70710678118654752f));
    }
    __syncthreads();
    if (t < 128) {
      float a = 0;
      for (int j = 0; j < 16; j++) a += sh[j]*fc2[j*128+t];
      attc[b*128+t] = 1.0f/(1.0f + __expf(-a));
    }
    __syncthreads();
  }
}

// ---------------- pooling (16x16 mean) of [xn|xen] ----------------
__global__ void pool_kernel(const float* __restrict__ xn, const float* __restrict__ xen,
                            float* __restrict__ pool){
  int cellb = blockIdx.x;        // b*49+cell
  int py = blockIdx.y;           // 0..7, two i-rows each
  int c = threadIdx.x;           // 0..191
  int b = cellb / 49, cell = cellb % 49;
  int wy = cell / 7, wx = cell % 7;
  float s = 0;
  for (int i = py*2; i < py*2+2; i++)
    for (int j = 0; j < 16; j++) {
      int y = wy*16+i, x = wx*16+j;
      size_t row = (size_t)(b*112+y)*112 + x;
      s += (c < 128) ? xn[row*128 + c] : xen[row*64 + (c-128)];
    }
  atomicAdd(&pool[(size_t)cellb*192 + c], s);
}

// ---------------- q projection (pool/256 @ q_w + q_b) * 8^-0.5 ----------------
__global__ void qproj_kernel(const float* __restrict__ pool, const float* __restrict__ qw,
                             const float* __restrict__ qb, float* __restrict__ qbuf){
  int cellb = blockIdx.x;  // 392
  int j = threadIdx.x;     // 64
  float s = qb[j];
  for (int c = 0; c < 192; c++)
    s += pool[(size_t)cellb*192 + c] * (1.0f/256.0f) * qw[c*64 + j];
  qbuf[(size_t)cellb*64 + j] = s * 0.35355339059327373f;
}

// ---------------- flash attention, split-K partials ----------------
// grid 512: blk = b*64 + nh*8 + sp (8 splits of 1568 keys)
__global__ __launch_bounds__(256) void attn_kernel(const float* __restrict__ qbuf,
    const float* __restrict__ kv, float* __restrict__ part){
  __shared__ float qs[392];
  __shared__ float ks[256*8];
  __shared__ float vs[256*8];
  int t = threadIdx.x;
  int blk = blockIdx.x;
  int b = blk >> 6, nh = (blk >> 3) & 7, sp = blk & 7;
  for (int i = t; i < 392; i += 256)   // FIX: grid-stride (392 > 256 threads)
    qs[i] = qbuf[(size_t)(b*49 + (i>>3))*64 + nh*8 + (i&7)];
  __syncthreads();
  int lane = t & 63, w = t >> 6;
  int qq = lane < 49 ? lane : 0;
  float4 qa = *(const float4*)&qs[qq*8];
  float4 qb4 = *(const float4*)&qs[qq*8+4];
  float m = -1e30f, l = 0.f;
  float4 acca = make_float4(0,0,0,0), accb = make_float4(0,0,0,0);
  const int base = sp * 1568;
  for (int c0 = 0; c0 < 1568; c0 += 256) {
    int cnt = 1568 - c0 < 256 ? 1568 - c0 : 256;
    __syncthreads();
    if (t < cnt) {
      size_t rb = ((size_t)(b*HW + base + c0 + t))*128 + nh*8;
      *(float4*)&ks[t*8]   = *(const float4*)(kv + rb);
      *(float4*)&ks[t*8+4] = *(const float4*)(kv + rb + 4);
      *(float4*)&vs[t*8]   = *(const float4*)(kv + rb + 64);
      *(float4*)&vs[t*8+4] = *(const float4*)(kv + rb + 68);
    }
    __syncthreads();
    int s0 = w*64;
    int n = cnt - s0; if (n > 64) n = 64;
    for (int i = 0; i < n; i++) {
      const float* kp = &ks[(s0+i)*8];
      float4 ka = *(const float4*)kp, kb = *(const float4*)(kp+4);
      float s = qa.x*ka.x + qa.y*ka.y + qa.z*ka.z + qa.w*ka.w
              + qb4.x*kb.x + qb4.y*kb.y + qb4.z*kb.z + qb4.w*kb.w;
      float mn = fmaxf(m, s);
      float corr = __expf(m - mn);
      float pe   = __expf(s - mn);
      l = l*corr + pe;
      const float* vp = &vs[(s0+i)*8];
      float4 va = *(const float4*)vp, vb = *(const float4*)(vp+4);
      acca.x = acca.x*corr + pe*va.x; acca.y = acca.y*corr + pe*va.y;
      acca.z = acca.z*corr + pe*va.z; acca.w = acca.w*corr + pe*va.w;
      accb.x = accb.x*corr + pe*vb.x; accb.y = accb.y*corr + pe*vb.y;
      accb.z = accb.z*corr + pe*vb.z; accb.w = accb.w*corr + pe*vb.w;
      m = mn;
    }
  }
  if (lane < 49) {
    size_t idx = ((size_t)(blk*4 + w)*49 + lane)*10;
    part[idx] = m; part[idx+1] = l;
    part[idx+2] = acca.x; part[idx+3] = acca.y; part[idx+4] = acca.z; part[idx+5] = acca.w;
    part[idx+6] = accb.x; part[idx+7] = accb.y; part[idx+8] = accb.z; part[idx+9] = accb.w;
  }
}

__global__ void merge_kernel(const float* __restrict__ part, float* __restrict__ gsm){
  int g = blockIdx.x*64 + threadIdx.x;   // 3136 = 8*8*49
  if (g >= 3136) return;
  int b = g / 392, r = g % 392, nh = r / 49, q = r % 49;
  int blkbase = b*64 + nh*8;
  float M = -1e30f;
  for (int sp = 0; sp < 8; sp++)
    for (int w = 0; w < 4; w++) {
      size_t idx = ((size_t)((blkbase+sp)*4 + w)*49 + q)*10;
      M = fmaxf(M, part[idx]);
    }
  float L = 0, a[8] = {0,0,0,0,0,0,0,0};
  for (int sp = 0; sp < 8; sp++)
    for (int w = 0; w < 4; w++) {
      size_t idx = ((size_t)((blkbase+sp)*4 + w)*49 + q)*10;
      float c = __expf(part[idx] - M);
      L += part[idx+1]*c;
      #pragma unroll
      for (int d = 0; d < 8; d++) a[d] += part[idx+2+d]*c;
    }
  #pragma unroll
  for (int d = 0; d < 8; d++)
    gsm[(size_t)(b*49+q)*64 + nh*8 + d] = a[d]/L;
}

// ---------------- xc cols 128..191: bilinear(g) ----------------
__global__ __launch_bounds__(256) void f2_kernel(const float* __restrict__ gsm,
                                                 float* __restrict__ xc){
  int gidx = blockIdx.x*256 + threadIdx.x;   // N*64 total
  int r = gidx >> 6, cc = gidx & 63;
  int b = r / HW, rem = r % HW, y = rem / 112, x = rem % 112;
  float fy = fminf(fmaxf((y + 0.5f)*0.0625f - 0.5f, 0.f), 6.f);
  float fx = fminf(fmaxf((x + 0.5f)*0.0625f - 0.5f, 0.f), 6.f);
  int y0 = (int)fy, x0 = (int)fx;
  float wy = fy - y0, wx = fx - x0;
  int y1 = y0+1 < 6 ? y0+1 : 6, x1 = x0+1 < 6 ? x0+1 : 6;
  const float* gb = gsm + (size_t)b*49*64 + cc;
  float g00 = gb[(y0*7+x0)*64], g01 = gb[(y0*7+x1)*64];
  float g10 = gb[(y1*7+x0)*64], g11 = gb[(y1*7+x1)*64];
  xc[(size_t)r*256 + 128 + cc] =
      (1-wy)*((1-wx)*g00 + wx*g01) + wy*((1-wx)*g10 + wx*g11);
}

// =====================================================================
extern "C" void kernel_launch(void* const* d_in, const int* in_sizes, int n_in,
                              void* d_out, int out_size, void* d_ws, size_t ws_size,
                              hipStream_t stream) {
  const float* x      = (const float*)d_in[0];
  const float* x_e    = (const float*)d_in[1];
  const float* norm_w = (const float*)d_in[2];
  const float* norm_b = (const float*)d_in[3];
  const float* norme_w= (const float*)d_in[4];
  const float* norme_b= (const float*)d_in[5];
  const float* rr1_w  = (const float*)d_in[6];
  const float* rr1_b  = (const float*)d_in[7];
  const float* rr2_w  = (const float*)d_in[8];
  const float* rr2_b  = (const float*)d_in[9];
  const float* rr3_w  = (const float*)d_in[10];
  const float* rr3_b  = (const float*)d_in[11];
  const float* conv_w = (const float*)d_in[12];
  const float* conv_b = (const float*)d_in[13];
  const float* la1_w  = (const float*)d_in[14];
  const float* la1_b  = (const float*)d_in[15];
  const float* la2_w  = (const float*)d_in[16];
  const float* la2_b  = (const float*)d_in[17];
  const float* lac1_w = (const float*)d_in[18];
  const float* lac1_b = (const float*)d_in[19];
  const float* lac2_w = (const float*)d_in[20];
  const float* lac2_b = (const float*)d_in[21];
  const float* fc1_w  = (const float*)d_in[22];
  const float* fc2_w  = (const float*)d_in[23];
  const float* la3_w  = (const float*)d_in[24];
  const float* la3_b  = (const float*)d_in[25];
  const float* kv_w   = (const float*)d_in[26];
  const float* kv_b   = (const float*)d_in[27];
  const float* q_w    = (const float*)d_in[28];
  const float* q_b    = (const float*)d_in[29];
  const float* proj_w = (const float*)d_in[30];
  const float* proj_b = (const float*)d_in[31];
  const float* proje_w= (const float*)d_in[32];
  const float* proje_b= (const float*)d_in[33];

  const size_t N = N_POS;
  float* ws   = (float*)d_ws;
  // Lifetime-overlaid workspace plan (~261 MB):
  float* rr1   = ws;                 // N*128, G1 out, dead after G3
  float* xnbuf = ws + N*128;         // N*128: xn -> convout
  float* kvbuf = ws + N*256;         // N*128: kv -> codi
  float* xcbuf = ws + N*384;         // N*256: [rr2a(128) | rgb(64) | xen/t(64)] -> xc
  float* pool  = ws + N*640;         // 75264
  float* qbuf  = pool + 75264;       // 25088
  float* part  = qbuf + 25088;       // 512*4*49*10 = 1003520
  float* gsm   = part + 1003520;     // 25088
  float* dotb  = gsm  + 25088;       // 1024
  float* n1sq  = dotb + 1024;        // 8
  float* n2sq  = n1sq + 8;           // 1024
  float* attc  = n2sq + 1024;        // 1024

  float* xn   = xnbuf;
  float* convout = xnbuf;            // reuse after G1
  float* kv   = kvbuf;
  float* codi = kvbuf;               // reuse after attn
  float* rr2a = xcbuf;               // [N][128]
  float* rgb  = xcbuf + N*128;       // [N][64]
  float* xen  = xcbuf + N*192;       // [N][64], becomes t in-place
  float* xc   = xcbuf;               // [N][256] final layout
  float* outp = (float*)d_out;
  float* oute = outp + N*128;

  // 1. zero accumulators (pool, dotb+n1sq+n2sq = 2056)
  zero_kernel<<<(75264+255)/256, 256, 0, stream>>>(pool, 75264);
  zero_kernel<<<9, 256, 0, stream>>>(dotb, 2056);
  // 2. layernorms
  ln128_kernel<<<N_POS/4, 256, 0, stream>>>(x, norm_w, norm_b, xn);
  ln64_kernel <<<N_POS/4, 256, 0, stream>>>(x_e, norme_w, norme_b, xen);
  // 3. pool + q projection
  pool_kernel<<<dim3(392,8), 192, 0, stream>>>(xn, xen, pool);
  qproj_kernel<<<392, 64, 0, stream>>>(pool, q_w, q_b, qbuf);
  // 4. G1: xn -> rr1 | rr2a | rgb | kv
  {
    GemmParams p; p.A = xn; p.scale = 0; p.lda = 128; p.K = 128; p.rowsPerB = HW;
    p.tiles[0] = {rr1_w,    rr1_b,    rr1,     0, 128, 128, 0};
    p.tiles[1] = {rr1_w+64, rr1_b+64, rr1+64,  0, 128, 128, 0};
    p.tiles[2] = {rr2_w,    rr2_b,    rr2a,    0, 128, 128, 0};
    p.tiles[3] = {rr2_w+64, rr2_b+64, rr2a+64, 0, 128, 128, 0};
    p.tiles[4] = {la1_w,    la1_b,    rgb,     0,  64,  64, 0};
    p.tiles[5] = {kv_w,     kv_b,     kv,      0, 128, 128, 0};
    p.tiles[6] = {kv_w+64,  kv_b+64,  kv+64,   0, 128, 128, 0};
    gemm_tiled<<<dim3(1568,7), 256, 0, stream>>>(p);
  }
  // 5. pooled attention (consumes kv; kvbuf free afterwards)
  attn_kernel<<<512, 256, 0, stream>>>(qbuf, kv, part);
  merge_kernel<<<49, 64, 0, stream>>>(part, gsm);
  // 6. G2: xen -> t  (in-place: BK=64 stages all A rows before writes)
  {
    GemmParams p; p.A = xen; p.scale = 0; p.lda = 64; p.K = 64; p.rowsPerB = HW;
    p.tiles[0] = {la2_w, la2_b, xen, 0, 64, 64, 0};
    gemm_tiled<<<dim3(1568,1), 256, 0, stream>>>(p);
  }
  // 7. co/di convs -> codi (in kvbuf)
  dwconv_codi_kernel<<<N_POS/2, 256, 0, stream>>>(rgb, xen, lac1_w, lac1_b, lac2_w, lac2_b, codi);
  // 8. dwconv on rr2a -> convout (in xnbuf; xn dead)
  dwconv128_kernel<<<N_POS/2, 256, 0, stream>>>(rr2a, conv_w, conv_b, convout);
  // 9. G3 fused gate: (convout@rr3 + b) * rr1 -> xc cols 0..127
  //    (xc overlays rr2a|rgb|xen, all dead now)
  {
    GemmParams p; p.A = convout; p.scale = 0; p.lda = 128; p.K = 128; p.rowsPerB = HW;
    p.tiles[0] = {rr3_w,    rr3_b,    xc,      rr1,    128, 256, 128};
    p.tiles[1] = {rr3_w+64, rr3_b+64, xc+64,   rr1+64, 128, 256, 128};
    gemm_tiled<<<dim3(1568,2), 256, 0, stream>>>(p);
  }
  // 10. cosine gate
  reduce_kernel<<<392, 256, 0, stream>>>(codi, dotb, n1sq, n2sq);
  attc_kernel<<<1, 256, 0, stream>>>(dotb, n1sq, n2sq, fc1_w, fc2_w, attc);
  // 11. G4: (codi * attc) @ la3 -> xc cols 192..255
  {
    GemmParams p; p.A = codi; p.scale = attc; p.lda = 128; p.K = 128; p.rowsPerB = HW;
    p.tiles[0] = {la3_w, la3_b, xc + 192, 0, 64, 256, 0};
    gemm_tiled<<<dim3(1568,1), 256, 0, stream>>>(p);
  }
  // 12. xc cols 128..191: bilinear upsample of g
  f2_kernel<<<25088, 256, 0, stream>>>(gsm, xc);
  // 13. G5: xc -> out | out_e
  {
    GemmParams p; p.A = xc; p.scale = 0; p.lda = 256; p.K = 256; p.rowsPerB = HW;
    p.tiles[0] = {proj_w,    proj_b,    outp,    0, 128, 128, 0};
    p.tiles[1] = {proj_w+64, proj_b+64, outp+64, 0, 128, 128, 0};
    p.tiles[2] = {proje_w,   proje_b,   oute,    0,  64,  64, 0};
    gemm_tiled<<<dim3(1568,3), 256, 0, stream>>>(p);
  }
}

// Round 4
// 898.651 us; speedup vs baseline: 1.9092x; 1.9092x over previous
//
#include <hip/hip_runtime.h>
#include <math.h>

#define N_POS 100352   // 8*112*112
#define HW    12544    // 112*112

__device__ __forceinline__ void fma4(float4& c, float s, const float4 w){
  c.x = fmaf(s, w.x, c.x); c.y = fmaf(s, w.y, c.y);
  c.z = fmaf(s, w.z, c.z); c.w = fmaf(s, w.w, c.w);
}

// ---------------- zero ----------------
__global__ void zero_kernel(float* p, int n){
  int i = blockIdx.x*256 + threadIdx.x;
  if (i < n) p[i] = 0.f;
}

// ---------------- LayerNorm (128 ch), one wave per row ----------------
__global__ __launch_bounds__(256) void ln128_kernel(const float* __restrict__ in,
    const float* __restrict__ w, const float* __restrict__ b, float* __restrict__ out){
  int row  = blockIdx.x*4 + (threadIdx.x >> 6);
  int lane = threadIdx.x & 63;
  const float* p = in + (size_t)row*128;
  float2 v = *(const float2*)(p + lane*2);
  float s = v.x + v.y;
  #pragma unroll
  for (int o = 1; o < 64; o <<= 1) s += __shfl_xor(s, o);
  float mu = s * (1.0f/128.0f);
  float dx = v.x - mu, dy = v.y - mu;
  float q = dx*dx + dy*dy;
  #pragma unroll
  for (int o = 1; o < 64; o <<= 1) q += __shfl_xor(q, o);
  float rs = rsqrtf(q * (1.0f/128.0f) + 1e-6f);
  int c = lane*2;
  float2 o2;
  o2.x = dx*rs*w[c]   + b[c];
  o2.y = dy*rs*w[c+1] + b[c+1];
  *(float2*)(out + (size_t)row*128 + c) = o2;
}

// ---------------- LayerNorm (64 ch) ----------------
__global__ __launch_bounds__(256) void ln64_kernel(const float* __restrict__ in,
    const float* __restrict__ w, const float* __restrict__ b, float* __restrict__ out){
  int row  = blockIdx.x*4 + (threadIdx.x >> 6);
  int lane = threadIdx.x & 63;
  float v = in[(size_t)row*64 + lane];
  float s = v;
  #pragma unroll
  for (int o = 1; o < 64; o <<= 1) s += __shfl_xor(s, o);
  float mu = s * (1.0f/64.0f);
  float d = v - mu;
  float q = d*d;
  #pragma unroll
  for (int o = 1; o < 64; o <<= 1) q += __shfl_xor(q, o);
  float rs = rsqrtf(q * (1.0f/64.0f) + 1e-6f);
  out[(size_t)row*64 + lane] = d*rs*w[lane] + b[lane];
}

// ---------------- generic tiled fp32 GEMM ----------------
struct ColTile {
  const float* W; const float* bias; float* out; const float* mult;
  int ldw; int ldo; int ldm;
};
struct GemmParams {
  const float* A; const float* scale;
  int lda; int K; int rowsPerB;
  ColTile tiles[8];
};

__global__ __launch_bounds__(256,2) void gemm_tiled(GemmParams p){
  __shared__ float As[64*68];   // [m][k] stride 68
  __shared__ float Ws[64*64];   // [k][n]
  const int tid = threadIdx.x;
  const int tx = tid & 15, ty = tid >> 4;
  const int kk = tx*4;
  const int row0 = blockIdx.x * 64;
  ColTile tile = p.tiles[blockIdx.y];
  float4 acc0 = make_float4(0,0,0,0), acc1 = acc0, acc2 = acc0, acc3 = acc0;
  const float* scale = p.scale ? (p.scale + (size_t)(row0 / p.rowsPerB) * p.K) : (const float*)0;

  for (int k0 = 0; k0 < p.K; k0 += 64) {
    #pragma unroll
    for (int m = ty; m < 64; m += 16) {
      float4 a = *(const float4*)(p.A + (size_t)(row0+m)*p.lda + k0 + kk);
      if (scale) {
        a.x *= scale[k0+kk]; a.y *= scale[k0+kk+1];
        a.z *= scale[k0+kk+2]; a.w *= scale[k0+kk+3];
      }
      *(float4*)&As[m*68 + kk] = a;
    }
    #pragma unroll
    for (int k = ty; k < 64; k += 16)
      *(float4*)&Ws[k*64 + kk] = *(const float4*)(tile.W + (size_t)(k0+k)*tile.ldw + kk);
    __syncthreads();
    #pragma unroll 4
    for (int k = 0; k < 64; k += 4) {
      float4 w0 = *(const float4*)&Ws[(k+0)*64 + kk];
      float4 w1 = *(const float4*)&Ws[(k+1)*64 + kk];
      float4 w2 = *(const float4*)&Ws[(k+2)*64 + kk];
      float4 w3 = *(const float4*)&Ws[(k+3)*64 + kk];
      float4 a0 = *(const float4*)&As[(ty*4+0)*68 + k];
      float4 a1 = *(const float4*)&As[(ty*4+1)*68 + k];
      float4 a2 = *(const float4*)&As[(ty*4+2)*68 + k];
      float4 a3 = *(const float4*)&As[(ty*4+3)*68 + k];
      fma4(acc0,a0.x,w0); fma4(acc0,a0.y,w1); fma4(acc0,a0.z,w2); fma4(acc0,a0.w,w3);
      fma4(acc1,a1.x,w0); fma4(acc1,a1.y,w1); fma4(acc1,a1.z,w2); fma4(acc1,a1.w,w3);
      fma4(acc2,a2.x,w0); fma4(acc2,a2.y,w1); fma4(acc2,a2.z,w2); fma4(acc2,a2.w,w3);
      fma4(acc3,a3.x,w0); fma4(acc3,a3.y,w1); fma4(acc3,a3.z,w2); fma4(acc3,a3.w,w3);
    }
    __syncthreads();
  }
  float4 bias = *(const float4*)(tile.bias + kk);
  float4 accs[4] = {acc0, acc1, acc2, acc3};
  #pragma unroll
  for (int i = 0; i < 4; i++) {
    int row = row0 + ty*4 + i;
    float4 o;
    o.x = accs[i].x + bias.x; o.y = accs[i].y + bias.y;
    o.z = accs[i].z + bias.z; o.w = accs[i].w + bias.w;
    if (tile.mult) {
      float4 mv = *(const float4*)(tile.mult + (size_t)row*tile.ldm + kk);
      o.x *= mv.x; o.y *= mv.y; o.z *= mv.z; o.w *= mv.w;
    }
    *(float4*)(tile.out + (size_t)row*tile.ldo + kk) = o;
  }
}

// ---------------- 7x7 depthwise conv, 128 ch, register-sliding x-strip ----------------
// lane=channel (coalesced 256B loads); thread computes 8 consecutive x outputs.
// Per ky: load 14-wide strip once, 7-tap kx conv over registers.
__global__ __launch_bounds__(256) void dwconv128_kernel(const float* __restrict__ in,
    const float* __restrict__ cw, const float* __restrict__ cb, float* __restrict__ out){
  __shared__ float wsm[128*49];
  int t = threadIdx.x;
  for (int i = t; i < 128*49; i += 256) wsm[i] = cw[i];
  __syncthreads();
  int c = t & 127;
  int wv = t >> 7;                    // 0..1: y sub-row
  int blk = blockIdx.x;               // 8 * 56 * 14
  int xs = blk % 14; int tmp = blk / 14;
  int yg = tmp % 56; int b = tmp / 56;
  int y = yg*2 + wv;
  int x0 = xs*8;
  const float* wp = &wsm[c*49];
  float acc[8];
  float bias = cb[c];
  #pragma unroll
  for (int i = 0; i < 8; i++) acc[i] = bias;
  for (int ky = 0; ky < 7; ky++) {
    int yy = y + ky - 3;
    if ((unsigned)yy >= 112u) continue;           // wave-uniform
    const float* row = in + ((size_t)(b*112+yy)*112)*128 + c;
    float v[14];
    #pragma unroll
    for (int i = 0; i < 14; i++) {
      int xx = x0 + i - 3;
      v[i] = ((unsigned)xx < 112u) ? row[(size_t)xx*128] : 0.f;
    }
    #pragma unroll
    for (int kx = 0; kx < 7; kx++) {
      float w = wp[ky*7+kx];
      #pragma unroll
      for (int i = 0; i < 8; i++) acc[i] = fmaf(w, v[i+kx], acc[i]);
    }
  }
  size_t rowbase = (size_t)(b*112+y)*112 + x0;
  #pragma unroll
  for (int i = 0; i < 8; i++) out[(rowbase+i)*128 + c] = acc[i];
}

// ---------------- co/di fused dwconv, register-sliding ----------------
__global__ __launch_bounds__(256) void dwconv_codi_kernel(
    const float* __restrict__ rgb, const float* __restrict__ tb,
    const float* __restrict__ w1, const float* __restrict__ b1,
    const float* __restrict__ w2, const float* __restrict__ b2,
    float* __restrict__ out){
  __shared__ float wsm[2*64*49];
  int t = threadIdx.x;
  for (int i = t; i < 2*64*49; i += 256) wsm[i] = (i < 3136) ? w1[i] : w2[i-3136];
  __syncthreads();
  int lane = t & 63;                  // channel
  int wv = t >> 6;                    // 0..3: y sub-row
  int blk = blockIdx.x;               // 8 * 28 * 14
  int xs = blk % 14; int tmp = blk / 14;
  int yg = tmp % 28; int b = tmp / 28;
  int y = yg*4 + wv;
  int x0 = xs*8;
  const float* wco = &wsm[lane*49];
  const float* wdi = &wsm[3136 + lane*49];
  float acc_co[8], acc_di[8];
  float bco = b1[lane], bdi = b2[lane];
  #pragma unroll
  for (int i = 0; i < 8; i++) { acc_co[i] = bco; acc_di[i] = bdi; }
  for (int ky = 0; ky < 7; ky++) {
    int yy = y + ky - 3;
    if ((unsigned)yy >= 112u) continue;           // wave-uniform
    const float* rrow = rgb + ((size_t)(b*112+yy)*112)*64 + lane;
    const float* trow = tb  + ((size_t)(b*112+yy)*112)*64 + lane;
    float p[14], d[14];
    #pragma unroll
    for (int i = 0; i < 14; i++) {
      int xx = x0 + i - 3;
      float a = 0.f, bb = 0.f;
      if ((unsigned)xx < 112u) { a = rrow[(size_t)xx*64]; bb = trow[(size_t)xx*64]; }
      p[i] = a*bb; d[i] = fabsf(a-bb);
    }
    #pragma unroll
    for (int kx = 0; kx < 7; kx++) {
      float wc = wco[ky*7+kx], wd = wdi[ky*7+kx];
      #pragma unroll
      for (int i = 0; i < 8; i++) {
        acc_co[i] = fmaf(wc, p[i+kx], acc_co[i]);
        acc_di[i] = fmaf(wd, d[i+kx], acc_di[i]);
      }
    }
  }
  size_t rowbase = (size_t)(b*112+y)*112 + x0;
  #pragma unroll
  for (int i = 0; i < 8; i++) {
    out[(rowbase+i)*128 + lane]      = acc_co[i];
    out[(rowbase+i)*128 + 64 + lane] = acc_di[i];
  }
}

// ---------------- cosine-gate reductions ----------------
__global__ __launch_bounds__(256) void reduce_kernel(const float* __restrict__ codi,
    float* __restrict__ dotb, float* __restrict__ n1sq, float* __restrict__ n2sq){
  int blk = blockIdx.x;          // 392 = 8 b * 49 segs
  int b = blk / 49, seg = blk % 49;
  int lane = threadIdx.x & 63, w = threadIdx.x >> 6;
  int c = lane*2;
  float d0=0,d1=0,s0=0,s1=0,a1=0;
  for (int i = 0; i < 64; i++) {
    int row = b*HW + seg*256 + w*64 + i;
    float2 v = *(const float2*)(codi + (size_t)row*128 + c);
    float rs = v.x + v.y;
    #pragma unroll
    for (int o = 1; o < 64; o <<= 1) rs += __shfl_xor(rs, o);
    float amap = rs * (1.0f/128.0f);
    d0 += amap*v.x; d1 += amap*v.y;
    s0 += v.x*v.x;  s1 += v.y*v.y;
    if (lane == 0) a1 += amap*amap;
  }
  atomicAdd(&dotb[b*128+c],   d0); atomicAdd(&dotb[b*128+c+1], d1);
  atomicAdd(&n2sq[b*128+c],   s0); atomicAdd(&n2sq[b*128+c+1], s1);
  if (lane == 0) atomicAdd(&n1sq[b], a1);
}

__global__ __launch_bounds__(256) void attc_kernel(const float* __restrict__ dotb,
    const float* __restrict__ n1sq, const float* __restrict__ n2sq,
    const float* __restrict__ fc1, const float* __restrict__ fc2, float* __restrict__ attc){
  __shared__ float scos[128];
  __shared__ float sh[16];
  int t = threadIdx.x;
  for (int b = 0; b < 8; b++) {
    if (t < 128) {
      float n1 = sqrtf(n1sq[b]);
      float n2 = sqrtf(n2sq[b*128+t]);
      scos[t] = dotb[b*128+t] / (n1*n2 + 1e-6f);
    }
    __syncthreads();
    if (t < 16) {
      float h = 0;
      for (int c = 0; c < 128; c++) h += scos[c]*fc1[c*16+t];
      sh[t] = h * 0.5f * (1.0f + erff(h*0.70710678118654752f));
    }
    __syncthreads();
    if (t < 128) {
      float a = 0;
      for (int j = 0; j < 16; j++) a += sh[j]*fc2[j*128+t];
      attc[b*128+t] = 1.0f/(1.0f + __expf(-a));
    }
    __syncthreads();
  }
}

// ---------------- pooling (16x16 mean) of [xn|xen] ----------------
__global__ void pool_kernel(const float* __restrict__ xn, const float* __restrict__ xen,
                            float* __restrict__ pool){
  int cellb = blockIdx.x;        // b*49+cell
  int py = blockIdx.y;           // 0..7, two i-rows each
  int c = threadIdx.x;           // 0..191
  int b = cellb / 49, cell = cellb % 49;
  int wy = cell / 7, wx = cell % 7;
  float s = 0;
  for (int i = py*2; i < py*2+2; i++)
    for (int j = 0; j < 16; j++) {
      int y = wy*16+i, x = wx*16+j;
      size_t row = (size_t)(b*112+y)*112 + x;
      s += (c < 128) ? xn[row*128 + c] : xen[row*64 + (c-128)];
    }
  atomicAdd(&pool[(size_t)cellb*192 + c], s);
}

// ---------------- q projection (pool/256 @ q_w + q_b) * 8^-0.5 ----------------
__global__ void qproj_kernel(const float* __restrict__ pool, const float* __restrict__ qw,
                             const float* __restrict__ qb, float* __restrict__ qbuf){
  int cellb = blockIdx.x;  // 392
  int j = threadIdx.x;     // 64
  float s = qb[j];
  for (int c = 0; c < 192; c++)
    s += pool[(size_t)cellb*192 + c] * (1.0f/256.0f) * qw[c*64 + j];
  qbuf[(size_t)cellb*64 + j] = s * 0.35355339059327373f;
}

// ---------------- flash attention, split-K partials ----------------
__global__ __launch_bounds__(256) void attn_kernel(const float* __restrict__ qbuf,
    const float* __restrict__ kv, float* __restrict__ part){
  __shared__ float qs[392];
  __shared__ float ks[256*8];
  __shared__ float vs[256*8];
  int t = threadIdx.x;
  int blk = blockIdx.x;
  int b = blk >> 6, nh = (blk >> 3) & 7, sp = blk & 7;
  for (int i = t; i < 392; i += 256)
    qs[i] = qbuf[(size_t)(b*49 + (i>>3))*64 + nh*8 + (i&7)];
  __syncthreads();
  int lane = t & 63, w = t >> 6;
  int qq = lane < 49 ? lane : 0;
  float4 qa = *(const float4*)&qs[qq*8];
  float4 qb4 = *(const float4*)&qs[qq*8+4];
  float m = -1e30f, l = 0.f;
  float4 acca = make_float4(0,0,0,0), accb = make_float4(0,0,0,0);
  const int base = sp * 1568;
  for (int c0 = 0; c0 < 1568; c0 += 256) {
    int cnt = 1568 - c0 < 256 ? 1568 - c0 : 256;
    __syncthreads();
    if (t < cnt) {
      size_t rb = ((size_t)(b*HW + base + c0 + t))*128 + nh*8;
      *(float4*)&ks[t*8]   = *(const float4*)(kv + rb);
      *(float4*)&ks[t*8+4] = *(const float4*)(kv + rb + 4);
      *(float4*)&vs[t*8]   = *(const float4*)(kv + rb + 64);
      *(float4*)&vs[t*8+4] = *(const float4*)(kv + rb + 68);
    }
    __syncthreads();
    int s0 = w*64;
    int n = cnt - s0; if (n > 64) n = 64;
    for (int i = 0; i < n; i++) {
      const float* kp = &ks[(s0+i)*8];
      float4 ka = *(const float4*)kp, kb = *(const float4*)(kp+4);
      float s = qa.x*ka.x + qa.y*ka.y + qa.z*ka.z + qa.w*ka.w
              + qb4.x*kb.x + qb4.y*kb.y + qb4.z*kb.z + qb4.w*kb.w;
      float mn = fmaxf(m, s);
      float corr = __expf(m - mn);
      float pe   = __expf(s - mn);
      l = l*corr + pe;
      const float* vp = &vs[(s0+i)*8];
      float4 va = *(const float4*)vp, vb = *(const float4*)(vp+4);
      acca.x = acca.x*corr + pe*va.x; acca.y = acca.y*corr + pe*va.y;
      acca.z = acca.z*corr + pe*va.z; acca.w = acca.w*corr + pe*va.w;
      accb.x = accb.x*corr + pe*vb.x; accb.y = accb.y*corr + pe*vb.y;
      accb.z = accb.z*corr + pe*vb.z; accb.w = accb.w*corr + pe*vb.w;
      m = mn;
    }
  }
  if (lane < 49) {
    size_t idx = ((size_t)(blk*4 + w)*49 + lane)*10;
    part[idx] = m; part[idx+1] = l;
    part[idx+2] = acca.x; part[idx+3] = acca.y; part[idx+4] = acca.z; part[idx+5] = acca.w;
    part[idx+6] = accb.x; part[idx+7] = accb.y; part[idx+8] = accb.z; part[idx+9] = accb.w;
  }
}

__global__ void merge_kernel(const float* __restrict__ part, float* __restrict__ gsm){
  int g = blockIdx.x*64 + threadIdx.x;   // 3136 = 8*8*49
  if (g >= 3136) return;
  int b = g / 392, r = g % 392, nh = r / 49, q = r % 49;
  int blkbase = b*64 + nh*8;
  float M = -1e30f;
  for (int sp = 0; sp < 8; sp++)
    for (int w = 0; w < 4; w++) {
      size_t idx = ((size_t)((blkbase+sp)*4 + w)*49 + q)*10;
      M = fmaxf(M, part[idx]);
    }
  float L = 0, a[8] = {0,0,0,0,0,0,0,0};
  for (int sp = 0; sp < 8; sp++)
    for (int w = 0; w < 4; w++) {
      size_t idx = ((size_t)((blkbase+sp)*4 + w)*49 + q)*10;
      float c = __expf(part[idx] - M);
      L += part[idx+1]*c;
      #pragma unroll
      for (int d = 0; d < 8; d++) a[d] += part[idx+2+d]*c;
    }
  #pragma unroll
  for (int d = 0; d < 8; d++)
    gsm[(size_t)(b*49+q)*64 + nh*8 + d] = a[d]/L;
}

// ---------------- xc cols 128..191: bilinear(g) ----------------
__global__ __launch_bounds__(256) void f2_kernel(const float* __restrict__ gsm,
                                                 float* __restrict__ xc){
  int gidx = blockIdx.x*256 + threadIdx.x;   // N*64 total
  int r = gidx >> 6, cc = gidx & 63;
  int b = r / HW, rem = r % HW, y = rem / 112, x = rem % 112;
  float fy = fminf(fmaxf((y + 0.5f)*0.0625f - 0.5f, 0.f), 6.f);
  float fx = fminf(fmaxf((x + 0.5f)*0.0625f - 0.5f, 0.f), 6.f);
  int y0 = (int)fy, x0 = (int)fx;
  float wy = fy - y0, wx = fx - x0;
  int y1 = y0+1 < 6 ? y0+1 : 6, x1 = x0+1 < 6 ? x0+1 : 6;
  const float* gb = gsm + (size_t)b*49*64 + cc;
  float g00 = gb[(y0*7+x0)*64], g01 = gb[(y0*7+x1)*64];
  float g10 = gb[(y1*7+x0)*64], g11 = gb[(y1*7+x1)*64];
  xc[(size_t)r*256 + 128 + cc] =
      (1-wy)*((1-wx)*g00 + wx*g01) + wy*((1-wx)*g10 + wx*g11);
}

// =====================================================================
extern "C" void kernel_launch(void* const* d_in, const int* in_sizes, int n_in,
                              void* d_out, int out_size, void* d_ws, size_t ws_size,
                              hipStream_t stream) {
  const float* x      = (const float*)d_in[0];
  const float* x_e    = (const float*)d_in[1];
  const float* norm_w = (const float*)d_in[2];
  const float* norm_b = (const float*)d_in[3];
  const float* norme_w= (const float*)d_in[4];
  const float* norme_b= (const float*)d_in[5];
  const float* rr1_w  = (const float*)d_in[6];
  const float* rr1_b  = (const float*)d_in[7];
  const float* rr2_w  = (const float*)d_in[8];
  const float* rr2_b  = (const float*)d_in[9];
  const float* rr3_w  = (const float*)d_in[10];
  const float* rr3_b  = (const float*)d_in[11];
  const float* conv_w = (const float*)d_in[12];
  const float* conv_b = (const float*)d_in[13];
  const float* la1_w  = (const float*)d_in[14];
  const float* la1_b  = (const float*)d_in[15];
  const float* la2_w  = (const float*)d_in[16];
  const float* la2_b  = (const float*)d_in[17];
  const float* lac1_w = (const float*)d_in[18];
  const float* lac1_b = (const float*)d_in[19];
  const float* lac2_w = (const float*)d_in[20];
  const float* lac2_b = (const float*)d_in[21];
  const float* fc1_w  = (const float*)d_in[22];
  const float* fc2_w  = (const float*)d_in[23];
  const float* la3_w  = (const float*)d_in[24];
  const float* la3_b  = (const float*)d_in[25];
  const float* kv_w   = (const float*)d_in[26];
  const float* kv_b   = (const float*)d_in[27];
  const float* q_w    = (const float*)d_in[28];
  const float* q_b    = (const float*)d_in[29];
  const float* proj_w = (const float*)d_in[30];
  const float* proj_b = (const float*)d_in[31];
  const float* proje_w= (const float*)d_in[32];
  const float* proje_b= (const float*)d_in[33];

  const size_t N = N_POS;
  float* ws   = (float*)d_ws;
  float* rr1   = ws;                 // N*128, dead after G3
  float* xnbuf = ws + N*128;         // N*128: xn -> convout
  float* kvbuf = ws + N*256;         // N*128: kv -> codi
  float* xcbuf = ws + N*384;         // N*256: [rr2a | rgb | xen/t] -> xc
  float* pool  = ws + N*640;         // 75264
  float* qbuf  = pool + 75264;       // 25088
  float* part  = qbuf + 25088;       // 1003520
  float* gsm   = part + 1003520;     // 25088
  float* dotb  = gsm  + 25088;       // 1024
  float* n1sq  = dotb + 1024;        // 8
  float* n2sq  = n1sq + 8;           // 1024
  float* attc  = n2sq + 1024;        // 1024

  float* xn   = xnbuf;
  float* convout = xnbuf;
  float* kv   = kvbuf;
  float* codi = kvbuf;
  float* rr2a = xcbuf;
  float* rgb  = xcbuf + N*128;
  float* xen  = xcbuf + N*192;
  float* xc   = xcbuf;
  float* outp = (float*)d_out;
  float* oute = outp + N*128;

  zero_kernel<<<(75264+255)/256, 256, 0, stream>>>(pool, 75264);
  zero_kernel<<<9, 256, 0, stream>>>(dotb, 2056);
  ln128_kernel<<<N_POS/4, 256, 0, stream>>>(x, norm_w, norm_b, xn);
  ln64_kernel <<<N_POS/4, 256, 0, stream>>>(x_e, norme_w, norme_b, xen);
  pool_kernel<<<dim3(392,8), 192, 0, stream>>>(xn, xen, pool);
  qproj_kernel<<<392, 64, 0, stream>>>(pool, q_w, q_b, qbuf);
  {
    GemmParams p; p.A = xn; p.scale = 0; p.lda = 128; p.K = 128; p.rowsPerB = HW;
    p.tiles[0] = {rr1_w,    rr1_b,    rr1,     0, 128, 128, 0};
    p.tiles[1] = {rr1_w+64, rr1_b+64, rr1+64,  0, 128, 128, 0};
    p.tiles[2] = {rr2_w,    rr2_b,    rr2a,    0, 128, 128, 0};
    p.tiles[3] = {rr2_w+64, rr2_b+64, rr2a+64, 0, 128, 128, 0};
    p.tiles[4] = {la1_w,    la1_b,    rgb,     0,  64,  64, 0};
    p.tiles[5] = {kv_w,     kv_b,     kv,      0, 128, 128, 0};
    p.tiles[6] = {kv_w+64,  kv_b+64,  kv+64,   0, 128, 128, 0};
    gemm_tiled<<<dim3(1568,7), 256, 0, stream>>>(p);
  }
  attn_kernel<<<512, 256, 0, stream>>>(qbuf, kv, part);
  merge_kernel<<<49, 64, 0, stream>>>(part, gsm);
  {
    GemmParams p; p.A = xen; p.scale = 0; p.lda = 64; p.K = 64; p.rowsPerB = HW;
    p.tiles[0] = {la2_w, la2_b, xen, 0, 64, 64, 0};
    gemm_tiled<<<dim3(1568,1), 256, 0, stream>>>(p);
  }
  dwconv_codi_kernel<<<8*28*14, 256, 0, stream>>>(rgb, xen, lac1_w, lac1_b, lac2_w, lac2_b, codi);
  dwconv128_kernel<<<8*56*14, 256, 0, stream>>>(rr2a, conv_w, conv_b, convout);
  {
    GemmParams p; p.A = convout; p.scale = 0; p.lda = 128; p.K = 128; p.rowsPerB = HW;
    p.tiles[0] = {rr3_w,    rr3_b,    xc,      rr1,    128, 256, 128};
    p.tiles[1] = {rr3_w+64, rr3_b+64, xc+64,   rr1+64, 128, 256, 128};
    gemm_tiled<<<dim3(1568,2), 256, 0, stream>>>(p);
  }
  reduce_kernel<<<392, 256, 0, stream>>>(codi, dotb, n1sq, n2sq);
  attc_kernel<<<1, 256, 0, stream>>>(dotb, n1sq, n2sq, fc1_w, fc2_w, attc);
  {
    GemmParams p; p.A = codi; p.scale = attc; p.lda = 128; p.K = 128; p.rowsPerB = HW;
    p.tiles[0] = {la3_w, la3_b, xc + 192, 0, 64, 256, 0};
    gemm_tiled<<<dim3(1568,1), 256, 0, stream>>>(p);
  }
  f2_kernel<<<25088, 256, 0, stream>>>(gsm, xc);
  {
    GemmParams p; p.A = xc; p.scale = 0; p.lda = 256; p.K = 256; p.rowsPerB = HW;
    p.tiles[0] = {proj_w,    proj_b,    outp,    0, 128, 128, 0};
    p.tiles[1] = {proj_w+64, proj_b+64, outp+64, 0, 128, 128, 0};
    p.tiles[2] = {proje_w,   proje_b,   oute,    0,  64,  64, 0};
    gemm_tiled<<<dim3(1568,3), 256, 0, stream>>>(p);
  }
}

// Round 5
// 829.297 us; speedup vs baseline: 2.0688x; 1.0836x over previous
//
#include <hip/hip_runtime.h>
#include <math.h>

#define N_POS 100352   // 8*112*112
#define HW    12544    // 112*112

typedef unsigned short bf16_t;
typedef __attribute__((ext_vector_type(8))) short bf16x8;
typedef __attribute__((ext_vector_type(4))) float f32x4;

__device__ __forceinline__ bf16_t f2b(float f){
  unsigned u = __builtin_bit_cast(unsigned, f);
  unsigned r = (u + 0x7fffu + ((u >> 16) & 1u)) >> 16;
  return (bf16_t)r;
}
__device__ __forceinline__ float b2f(bf16_t h){
  unsigned u = ((unsigned)h) << 16;
  return __builtin_bit_cast(float, u);
}

// ---------------- zero ----------------
__global__ void zero_kernel(float* p, int n){
  int i = blockIdx.x*256 + threadIdx.x;
  if (i < n) p[i] = 0.f;
}

// ---------------- weight transpose+cast: Wt[n][k] = bf16(W[k][n0+n]) ----------------
struct WJob { const float* src; bf16_t* dst; int K; int ldw; int n0; };
struct WJobs { WJob j[14]; };
__global__ void wtrans_kernel(WJobs js){
  WJob job = js.j[blockIdx.x];
  int t = threadIdx.x;
  int n = t & 63, k0 = t >> 6;
  for (int k = k0; k < job.K; k += 4)
    job.dst[(size_t)n*job.K + k] = f2b(job.src[(size_t)k*job.ldw + job.n0 + n]);
}

// ---------------- LayerNorm (128 ch) -> bf16 ----------------
__global__ __launch_bounds__(256) void ln128_kernel(const float* __restrict__ in,
    const float* __restrict__ w, const float* __restrict__ b, bf16_t* __restrict__ out){
  int row  = blockIdx.x*4 + (threadIdx.x >> 6);
  int lane = threadIdx.x & 63;
  const float* p = in + (size_t)row*128;
  float2 v = *(const float2*)(p + lane*2);
  float s = v.x + v.y;
  #pragma unroll
  for (int o = 1; o < 64; o <<= 1) s += __shfl_xor(s, o);
  float mu = s * (1.0f/128.0f);
  float dx = v.x - mu, dy = v.y - mu;
  float q = dx*dx + dy*dy;
  #pragma unroll
  for (int o = 1; o < 64; o <<= 1) q += __shfl_xor(q, o);
  float rs = rsqrtf(q * (1.0f/128.0f) + 1e-6f);
  int c = lane*2;
  ushort2 o2;
  o2.x = f2b(dx*rs*w[c]   + b[c]);
  o2.y = f2b(dy*rs*w[c+1] + b[c+1]);
  *(ushort2*)(out + (size_t)row*128 + c) = o2;
}

// ---------------- LayerNorm (64 ch) -> bf16 ----------------
__global__ __launch_bounds__(256) void ln64_kernel(const float* __restrict__ in,
    const float* __restrict__ w, const float* __restrict__ b, bf16_t* __restrict__ out){
  int row  = blockIdx.x*4 + (threadIdx.x >> 6);
  int lane = threadIdx.x & 63;
  float v = in[(size_t)row*64 + lane];
  float s = v;
  #pragma unroll
  for (int o = 1; o < 64; o <<= 1) s += __shfl_xor(s, o);
  float mu = s * (1.0f/64.0f);
  float d = v - mu;
  float q = d*d;
  #pragma unroll
  for (int o = 1; o < 64; o <<= 1) q += __shfl_xor(q, o);
  float rs = rsqrtf(q * (1.0f/64.0f) + 1e-6f);
  out[(size_t)row*64 + lane] = f2b(d*rs*w[lane] + b[lane]);
}

// ---------------- bf16 MFMA GEMM: 128x64 block, 4 waves x (32x64) ----------------
// out = [A(bf16, optionally col-scaled fp32) @ Wt^T + bias] (optionally * mult)
struct MTile {
  const bf16_t* Wt;    // [64][K] pre-transposed bf16
  const float* bias;
  void* out;           // bf16 or fp32 (out_fp32)
  const bf16_t* mult;  // optional gate, bf16 [row][ldm]
  int ldo; int ldm; int out_fp32;
};
struct MGemmParams {
  const bf16_t* A; const float* scale;  // scale fp32 [B][K] (col scale), may be null
  int lda; int K; int rowsPerB;
  MTile tiles[8];
};

__global__ __launch_bounds__(256) void mgemm(MGemmParams p){
  __shared__ short As[128*72];
  __shared__ short Ws[64*72];
  const int tid = threadIdx.x;
  const MTile tile = p.tiles[blockIdx.x];
  const int row0 = blockIdx.y * 128;
  const int lane = tid & 63, wv = tid >> 6;
  const int wm = wv * 32;
  const int fm = lane & 15;
  const int quad = lane >> 4;
  f32x4 acc[2][4];
  #pragma unroll
  for (int mi = 0; mi < 2; mi++)
    #pragma unroll
    for (int ni = 0; ni < 4; ni++) acc[mi][ni] = (f32x4)0.f;
  const float* scale = p.scale ? (p.scale + (size_t)(row0 / p.rowsPerB) * p.K) : (const float*)0;

  const int sr = tid & 127, sq = tid >> 7;       // A staging: row, 32-elem half
  const int wn = tid & 63,  wq = tid >> 6;       // W staging: n, 16-elem quarter

  for (int k0 = 0; k0 < p.K; k0 += 64) {
    // stage A[128][64] -> As (stride 72)
    {
      const bf16_t* src = p.A + (size_t)(row0 + sr)*p.lda + k0 + sq*32;
      short* dst = &As[sr*72 + sq*32];
      if (!scale) {
        #pragma unroll
        for (int i = 0; i < 4; i++)
          *(uint4*)(dst + i*8) = *(const uint4*)(src + i*8);
      } else {
        const float* sc = scale + k0 + sq*32;
        #pragma unroll
        for (int i = 0; i < 32; i++) dst[i] = (short)f2b(b2f(src[i]) * sc[i]);
      }
    }
    // stage Wt[64][64] -> Ws (stride 72)
    {
      const bf16_t* src = tile.Wt + (size_t)wn*p.K + k0 + wq*16;
      short* dst = &Ws[wn*72 + wq*16];
      *(uint4*)dst       = *(const uint4*)src;
      *(uint4*)(dst + 8) = *(const uint4*)(src + 8);
    }
    __syncthreads();
    #pragma unroll
    for (int ks = 0; ks < 2; ks++) {
      int kb = ks*32 + quad*8;
      bf16x8 af0 = *(const bf16x8*)&As[(wm + fm)*72 + kb];
      bf16x8 af1 = *(const bf16x8*)&As[(wm + 16 + fm)*72 + kb];
      bf16x8 bfr[4];
      #pragma unroll
      for (int ni = 0; ni < 4; ni++) bfr[ni] = *(const bf16x8*)&Ws[(ni*16 + fm)*72 + kb];
      #pragma unroll
      for (int ni = 0; ni < 4; ni++) {
        acc[0][ni] = __builtin_amdgcn_mfma_f32_16x16x32_bf16(af0, bfr[ni], acc[0][ni], 0, 0, 0);
        acc[1][ni] = __builtin_amdgcn_mfma_f32_16x16x32_bf16(af1, bfr[ni], acc[1][ni], 0, 0, 0);
      }
    }
    __syncthreads();
  }
  // epilogue: C/D layout col=lane&15, row=quad*4+reg
  #pragma unroll
  for (int mi = 0; mi < 2; mi++) {
    #pragma unroll
    for (int ni = 0; ni < 4; ni++) {
      int col = ni*16 + fm;
      float bias = tile.bias[col];
      #pragma unroll
      for (int r = 0; r < 4; r++) {
        int row = row0 + wm + mi*16 + quad*4 + r;
        float val = acc[mi][ni][r] + bias;
        if (tile.mult) val *= b2f(tile.mult[(size_t)row*tile.ldm + col]);
        if (tile.out_fp32) ((float*)tile.out)[(size_t)row*tile.ldo + col] = val;
        else ((bf16_t*)tile.out)[(size_t)row*tile.ldo + col] = f2b(val);
      }
    }
  }
}

// ---------------- 7x7 depthwise conv, 128 ch, bf16 in/out ----------------
__global__ __launch_bounds__(256) void dwconv128_kernel(const bf16_t* __restrict__ in,
    const float* __restrict__ cw, const float* __restrict__ cb, bf16_t* __restrict__ out){
  __shared__ float wsm[128*49];
  int t = threadIdx.x;
  for (int i = t; i < 128*49; i += 256) wsm[i] = cw[i];
  __syncthreads();
  int c = t & 127;
  int wv = t >> 7;
  int blk = blockIdx.x;               // 8 * 56 * 14
  int xs = blk % 14; int tmp = blk / 14;
  int yg = tmp % 56; int b = tmp / 56;
  int y = yg*2 + wv;
  int x0 = xs*8;
  const float* wp = &wsm[c*49];
  float acc[8];
  float bias = cb[c];
  #pragma unroll
  for (int i = 0; i < 8; i++) acc[i] = bias;
  for (int ky = 0; ky < 7; ky++) {
    int yy = y + ky - 3;
    if ((unsigned)yy >= 112u) continue;
    const bf16_t* row = in + ((size_t)(b*112+yy)*112)*128 + c;
    float v[14];
    #pragma unroll
    for (int i = 0; i < 14; i++) {
      int xx = x0 + i - 3;
      v[i] = ((unsigned)xx < 112u) ? b2f(row[(size_t)xx*128]) : 0.f;
    }
    #pragma unroll
    for (int kx = 0; kx < 7; kx++) {
      float w = wp[ky*7+kx];
      #pragma unroll
      for (int i = 0; i < 8; i++) acc[i] = fmaf(w, v[i+kx], acc[i]);
    }
  }
  size_t rowbase = (size_t)(b*112+y)*112 + x0;
  #pragma unroll
  for (int i = 0; i < 8; i++) out[(rowbase+i)*128 + c] = f2b(acc[i]);
}

// ---------------- co/di fused dwconv, bf16 in/out ----------------
__global__ __launch_bounds__(256) void dwconv_codi_kernel(
    const bf16_t* __restrict__ rgb, const bf16_t* __restrict__ tb,
    const float* __restrict__ w1, const float* __restrict__ b1,
    const float* __restrict__ w2, const float* __restrict__ b2,
    bf16_t* __restrict__ out){
  __shared__ float wsm[2*64*49];
  int t = threadIdx.x;
  for (int i = t; i < 2*64*49; i += 256) wsm[i] = (i < 3136) ? w1[i] : w2[i-3136];
  __syncthreads();
  int lane = t & 63;
  int wv = t >> 6;
  int blk = blockIdx.x;               // 8 * 28 * 14
  int xs = blk % 14; int tmp = blk / 14;
  int yg = tmp % 28; int b = tmp / 28;
  int y = yg*4 + wv;
  int x0 = xs*8;
  const float* wco = &wsm[lane*49];
  const float* wdi = &wsm[3136 + lane*49];
  float acc_co[8], acc_di[8];
  float bco = b1[lane], bdi = b2[lane];
  #pragma unroll
  for (int i = 0; i < 8; i++) { acc_co[i] = bco; acc_di[i] = bdi; }
  for (int ky = 0; ky < 7; ky++) {
    int yy = y + ky - 3;
    if ((unsigned)yy >= 112u) continue;
    const bf16_t* rrow = rgb + ((size_t)(b*112+yy)*112)*64 + lane;
    const bf16_t* trow = tb  + ((size_t)(b*112+yy)*112)*64 + lane;
    float p[14], d[14];
    #pragma unroll
    for (int i = 0; i < 14; i++) {
      int xx = x0 + i - 3;
      float a = 0.f, bb = 0.f;
      if ((unsigned)xx < 112u) { a = b2f(rrow[(size_t)xx*64]); bb = b2f(trow[(size_t)xx*64]); }
      p[i] = a*bb; d[i] = fabsf(a-bb);
    }
    #pragma unroll
    for (int kx = 0; kx < 7; kx++) {
      float wc = wco[ky*7+kx], wd = wdi[ky*7+kx];
      #pragma unroll
      for (int i = 0; i < 8; i++) {
        acc_co[i] = fmaf(wc, p[i+kx], acc_co[i]);
        acc_di[i] = fmaf(wd, d[i+kx], acc_di[i]);
      }
    }
  }
  size_t rowbase = (size_t)(b*112+y)*112 + x0;
  #pragma unroll
  for (int i = 0; i < 8; i++) {
    out[(rowbase+i)*128 + lane]      = f2b(acc_co[i]);
    out[(rowbase+i)*128 + 64 + lane] = f2b(acc_di[i]);
  }
}

// ---------------- cosine-gate reductions (codi bf16) ----------------
__global__ __launch_bounds__(256) void reduce_kernel(const bf16_t* __restrict__ codi,
    float* __restrict__ dotb, float* __restrict__ n1sq, float* __restrict__ n2sq){
  int blk = blockIdx.x;          // 392
  int b = blk / 49, seg = blk % 49;
  int lane = threadIdx.x & 63, w = threadIdx.x >> 6;
  int c = lane*2;
  float d0=0,d1=0,s0=0,s1=0,a1=0;
  for (int i = 0; i < 64; i++) {
    int row = b*HW + seg*256 + w*64 + i;
    ushort2 v2 = *(const ushort2*)(codi + (size_t)row*128 + c);
    float vx = b2f(v2.x), vy = b2f(v2.y);
    float rs = vx + vy;
    #pragma unroll
    for (int o = 1; o < 64; o <<= 1) rs += __shfl_xor(rs, o);
    float amap = rs * (1.0f/128.0f);
    d0 += amap*vx; d1 += amap*vy;
    s0 += vx*vx;   s1 += vy*vy;
    if (lane == 0) a1 += amap*amap;
  }
  atomicAdd(&dotb[b*128+c],   d0); atomicAdd(&dotb[b*128+c+1], d1);
  atomicAdd(&n2sq[b*128+c],   s0); atomicAdd(&n2sq[b*128+c+1], s1);
  if (lane == 0) atomicAdd(&n1sq[b], a1);
}

__global__ __launch_bounds__(256) void attc_kernel(const float* __restrict__ dotb,
    const float* __restrict__ n1sq, const float* __restrict__ n2sq,
    const float* __restrict__ fc1, const float* __restrict__ fc2, float* __restrict__ attc){
  __shared__ float scos[128];
  __shared__ float sh[16];
  int t = threadIdx.x;
  for (int b = 0; b < 8; b++) {
    if (t < 128) {
      float n1 = sqrtf(n1sq[b]);
      float n2 = sqrtf(n2sq[b*128+t]);
      scos[t] = dotb[b*128+t] / (n1*n2 + 1e-6f);
    }
    __syncthreads();
    if (t < 16) {
      float h = 0;
      for (int c = 0; c < 128; c++) h += scos[c]*fc1[c*16+t];
      sh[t] = h * 0.5f * (1.0f + erff(h*0.70710678118654752f));
    }
    __syncthreads();
    if (t < 128) {
      float a = 0;
      for (int j = 0; j < 16; j++) a += sh[j]*fc2[j*128+t];
      attc[b*128+t] = 1.0f/(1.0f + __expf(-a));
    }
    __syncthreads();
  }
}

// ---------------- pooling (16x16 mean) of [xn|xen] (bf16) ----------------
__global__ void pool_kernel(const bf16_t* __restrict__ xn, const bf16_t* __restrict__ xen,
                            float* __restrict__ pool){
  int cellb = blockIdx.x;
  int py = blockIdx.y;
  int c = threadIdx.x;           // 0..191
  int b = cellb / 49, cell = cellb % 49;
  int wy = cell / 7, wx = cell % 7;
  float s = 0;
  for (int i = py*2; i < py*2+2; i++)
    for (int j = 0; j < 16; j++) {
      int y = wy*16+i, x = wx*16+j;
      size_t row = (size_t)(b*112+y)*112 + x;
      s += (c < 128) ? b2f(xn[row*128 + c]) : b2f(xen[row*64 + (c-128)]);
    }
  atomicAdd(&pool[(size_t)cellb*192 + c], s);
}

// ---------------- q projection ----------------
__global__ void qproj_kernel(const float* __restrict__ pool, const float* __restrict__ qw,
                             const float* __restrict__ qb, float* __restrict__ qbuf){
  int cellb = blockIdx.x;
  int j = threadIdx.x;
  float s = qb[j];
  for (int c = 0; c < 192; c++)
    s += pool[(size_t)cellb*192 + c] * (1.0f/256.0f) * qw[c*64 + j];
  qbuf[(size_t)cellb*64 + j] = s * 0.35355339059327373f;
}

// ---------------- flash attention split-K (kv bf16) ----------------
__global__ __launch_bounds__(256) void attn_kernel(const float* __restrict__ qbuf,
    const bf16_t* __restrict__ kv, float* __restrict__ part){
  __shared__ float qs[392];
  __shared__ float ks[256*8];
  __shared__ float vs[256*8];
  int t = threadIdx.x;
  int blk = blockIdx.x;
  int b = blk >> 6, nh = (blk >> 3) & 7, sp = blk & 7;
  for (int i = t; i < 392; i += 256)
    qs[i] = qbuf[(size_t)(b*49 + (i>>3))*64 + nh*8 + (i&7)];
  __syncthreads();
  int lane = t & 63, w = t >> 6;
  int qq = lane < 49 ? lane : 0;
  float4 qa = *(const float4*)&qs[qq*8];
  float4 qb4 = *(const float4*)&qs[qq*8+4];
  float m = -1e30f, l = 0.f;
  float4 acca = make_float4(0,0,0,0), accb = make_float4(0,0,0,0);
  const int base = sp * 1568;
  for (int c0 = 0; c0 < 1568; c0 += 256) {
    int cnt = 1568 - c0 < 256 ? 1568 - c0 : 256;
    __syncthreads();
    if (t < cnt) {
      size_t rb = ((size_t)(b*HW + base + c0 + t))*128 + nh*8;
      uint4 kr = *(const uint4*)(kv + rb);
      uint4 vr = *(const uint4*)(kv + rb + 64);
      const bf16_t* kp = (const bf16_t*)&kr;
      const bf16_t* vp = (const bf16_t*)&vr;
      #pragma unroll
      for (int j = 0; j < 8; j++) { ks[t*8+j] = b2f(kp[j]); vs[t*8+j] = b2f(vp[j]); }
    }
    __syncthreads();
    int s0 = w*64;
    int n = cnt - s0; if (n > 64) n = 64;
    for (int i = 0; i < n; i++) {
      const float* kp = &ks[(s0+i)*8];
      float4 ka = *(const float4*)kp, kb = *(const float4*)(kp+4);
      float s = qa.x*ka.x + qa.y*ka.y + qa.z*ka.z + qa.w*ka.w
              + qb4.x*kb.x + qb4.y*kb.y + qb4.z*kb.z + qb4.w*kb.w;
      float mn = fmaxf(m, s);
      float corr = __expf(m - mn);
      float pe   = __expf(s - mn);
      l = l*corr + pe;
      const float* vp = &vs[(s0+i)*8];
      float4 va = *(const float4*)vp, vb = *(const float4*)(vp+4);
      acca.x = acca.x*corr + pe*va.x; acca.y = acca.y*corr + pe*va.y;
      acca.z = acca.z*corr + pe*va.z; acca.w = acca.w*corr + pe*va.w;
      accb.x = accb.x*corr + pe*vb.x; accb.y = accb.y*corr + pe*vb.y;
      accb.z = accb.z*corr + pe*vb.z; accb.w = accb.w*corr + pe*vb.w;
      m = mn;
    }
  }
  if (lane < 49) {
    size_t idx = ((size_t)(blk*4 + w)*49 + lane)*10;
    part[idx] = m; part[idx+1] = l;
    part[idx+2] = acca.x; part[idx+3] = acca.y; part[idx+4] = acca.z; part[idx+5] = acca.w;
    part[idx+6] = accb.x; part[idx+7] = accb.y; part[idx+8] = accb.z; part[idx+9] = accb.w;
  }
}

__global__ void merge_kernel(const float* __restrict__ part, float* __restrict__ gsm){
  int g = blockIdx.x*64 + threadIdx.x;   // 3136
  if (g >= 3136) return;
  int b = g / 392, r = g % 392, nh = r / 49, q = r % 49;
  int blkbase = b*64 + nh*8;
  float M = -1e30f;
  for (int sp = 0; sp < 8; sp++)
    for (int w = 0; w < 4; w++) {
      size_t idx = ((size_t)((blkbase+sp)*4 + w)*49 + q)*10;
      M = fmaxf(M, part[idx]);
    }
  float L = 0, a[8] = {0,0,0,0,0,0,0,0};
  for (int sp = 0; sp < 8; sp++)
    for (int w = 0; w < 4; w++) {
      size_t idx = ((size_t)((blkbase+sp)*4 + w)*49 + q)*10;
      float c = __expf(part[idx] - M);
      L += part[idx+1]*c;
      #pragma unroll
      for (int d = 0; d < 8; d++) a[d] += part[idx+2+d]*c;
    }
  #pragma unroll
  for (int d = 0; d < 8; d++)
    gsm[(size_t)(b*49+q)*64 + nh*8 + d] = a[d]/L;
}

// ---------------- xc cols 128..191: bilinear(g) -> bf16 ----------------
__global__ __launch_bounds__(256) void f2_kernel(const float* __restrict__ gsm,
                                                 bf16_t* __restrict__ xc){
  int gidx = blockIdx.x*256 + threadIdx.x;   // N*64 total
  int r = gidx >> 6, cc = gidx & 63;
  int b = r / HW, rem = r % HW, y = rem / 112, x = rem % 112;
  float fy = fminf(fmaxf((y + 0.5f)*0.0625f - 0.5f, 0.f), 6.f);
  float fx = fminf(fmaxf((x + 0.5f)*0.0625f - 0.5f, 0.f), 6.f);
  int y0 = (int)fy, x0 = (int)fx;
  float wy = fy - y0, wx = fx - x0;
  int y1 = y0+1 < 6 ? y0+1 : 6, x1 = x0+1 < 6 ? x0+1 : 6;
  const float* gb = gsm + (size_t)b*49*64 + cc;
  float g00 = gb[(y0*7+x0)*64], g01 = gb[(y0*7+x1)*64];
  float g10 = gb[(y1*7+x0)*64], g11 = gb[(y1*7+x1)*64];
  xc[(size_t)r*256 + 128 + cc] =
      f2b((1-wy)*((1-wx)*g00 + wx*g01) + wy*((1-wx)*g10 + wx*g11));
}

// =====================================================================
extern "C" void kernel_launch(void* const* d_in, const int* in_sizes, int n_in,
                              void* d_out, int out_size, void* d_ws, size_t ws_size,
                              hipStream_t stream) {
  const float* x      = (const float*)d_in[0];
  const float* x_e    = (const float*)d_in[1];
  const float* norm_w = (const float*)d_in[2];
  const float* norm_b = (const float*)d_in[3];
  const float* norme_w= (const float*)d_in[4];
  const float* norme_b= (const float*)d_in[5];
  const float* rr1_w  = (const float*)d_in[6];
  const float* rr1_b  = (const float*)d_in[7];
  const float* rr2_w  = (const float*)d_in[8];
  const float* rr2_b  = (const float*)d_in[9];
  const float* rr3_w  = (const float*)d_in[10];
  const float* rr3_b  = (const float*)d_in[11];
  const float* conv_w = (const float*)d_in[12];
  const float* conv_b = (const float*)d_in[13];
  const float* la1_w  = (const float*)d_in[14];
  const float* la1_b  = (const float*)d_in[15];
  const float* la2_w  = (const float*)d_in[16];
  const float* la2_b  = (const float*)d_in[17];
  const float* lac1_w = (const float*)d_in[18];
  const float* lac1_b = (const float*)d_in[19];
  const float* lac2_w = (const float*)d_in[20];
  const float* lac2_b = (const float*)d_in[21];
  const float* fc1_w  = (const float*)d_in[22];
  const float* fc2_w  = (const float*)d_in[23];
  const float* la3_w  = (const float*)d_in[24];
  const float* la3_b  = (const float*)d_in[25];
  const float* kv_w   = (const float*)d_in[26];
  const float* kv_b   = (const float*)d_in[27];
  const float* q_w    = (const float*)d_in[28];
  const float* q_b    = (const float*)d_in[29];
  const float* proj_w = (const float*)d_in[30];
  const float* proj_b = (const float*)d_in[31];
  const float* proje_w= (const float*)d_in[32];
  const float* proje_b= (const float*)d_in[33];

  const size_t N = N_POS;
  bf16_t* rr1   = (bf16_t*)d_ws;     // N*128 bf16, dead after G3
  bf16_t* xnbuf = rr1 + N*128;       // N*128: xn -> convout
  bf16_t* kvbuf = xnbuf + N*128;     // N*128: kv -> codi
  bf16_t* xcbuf = kvbuf + N*128;     // N*256: [rr2a | rgb | xen/t] -> xc
  float* pool = (float*)(xcbuf + N*256);  // 75264
  float* qbuf = pool + 75264;        // 25088
  float* part = qbuf + 25088;        // 1003520
  float* gsm  = part + 1003520;      // 25088
  float* dotb = gsm  + 25088;        // 1024
  float* n1sq = dotb + 1024;         // 8
  float* n2sq = n1sq + 8;            // 1024
  float* attc = n2sq + 1024;         // 1024
  bf16_t* wtab = (bf16_t*)(attc + 1024);  // 135168 shorts

  bf16_t* xn = xnbuf;
  bf16_t* convout = xnbuf;
  bf16_t* kv = kvbuf;
  bf16_t* codi = kvbuf;
  bf16_t* rr2a = xcbuf;
  bf16_t* rgb  = xcbuf + N*128;
  bf16_t* xen  = xcbuf + N*192;
  bf16_t* xc   = xcbuf;
  float* outp = (float*)d_out;
  float* oute = outp + N*128;

  // transposed-weight table offsets (shorts)
  bf16_t* rr1t0 = wtab;            bf16_t* rr1t1 = wtab + 8192;
  bf16_t* rr2t0 = wtab + 16384;    bf16_t* rr2t1 = wtab + 24576;
  bf16_t* la1t  = wtab + 32768;
  bf16_t* kvt0  = wtab + 40960;    bf16_t* kvt1  = wtab + 49152;
  bf16_t* la2t  = wtab + 57344;    // K=64
  bf16_t* rr3t0 = wtab + 61440;    bf16_t* rr3t1 = wtab + 69632;
  bf16_t* la3t  = wtab + 77824;
  bf16_t* projt0= wtab + 86016;    bf16_t* projt1= wtab + 102400;  // K=256
  bf16_t* projet= wtab + 118784;

  zero_kernel<<<(75264+255)/256, 256, 0, stream>>>(pool, 75264);
  zero_kernel<<<9, 256, 0, stream>>>(dotb, 2056);
  {
    WJobs js;
    js.j[0]  = {rr1_w,  rr1t0, 128, 128,   0};
    js.j[1]  = {rr1_w,  rr1t1, 128, 128,  64};
    js.j[2]  = {rr2_w,  rr2t0, 128, 128,   0};
    js.j[3]  = {rr2_w,  rr2t1, 128, 128,  64};
    js.j[4]  = {la1_w,  la1t,  128,  64,   0};
    js.j[5]  = {kv_w,   kvt0,  128, 128,   0};
    js.j[6]  = {kv_w,   kvt1,  128, 128,  64};
    js.j[7]  = {la2_w,  la2t,   64,  64,   0};
    js.j[8]  = {rr3_w,  rr3t0, 128, 128,   0};
    js.j[9]  = {rr3_w,  rr3t1, 128, 128,  64};
    js.j[10] = {la3_w,  la3t,  128,  64,   0};
    js.j[11] = {proj_w, projt0,256, 128,   0};
    js.j[12] = {proj_w, projt1,256, 128,  64};
    js.j[13] = {proje_w,projet,256,  64,   0};
    wtrans_kernel<<<14, 256, 0, stream>>>(js);
  }
  ln128_kernel<<<N_POS/4, 256, 0, stream>>>(x, norm_w, norm_b, xn);
  ln64_kernel <<<N_POS/4, 256, 0, stream>>>(x_e, norme_w, norme_b, xen);
  pool_kernel<<<dim3(392,8), 192, 0, stream>>>(xn, xen, pool);
  qproj_kernel<<<392, 64, 0, stream>>>(pool, q_w, q_b, qbuf);
  // G1: xn -> rr1 | rr2a | rgb | kv
  {
    MGemmParams p; p.A = xn; p.scale = 0; p.lda = 128; p.K = 128; p.rowsPerB = HW;
    p.tiles[0] = {rr1t0, rr1_b,    rr1,     0, 128, 0, 0};
    p.tiles[1] = {rr1t1, rr1_b+64, rr1+64,  0, 128, 0, 0};
    p.tiles[2] = {rr2t0, rr2_b,    rr2a,    0, 128, 0, 0};
    p.tiles[3] = {rr2t1, rr2_b+64, rr2a+64, 0, 128, 0, 0};
    p.tiles[4] = {la1t,  la1_b,    rgb,     0,  64, 0, 0};
    p.tiles[5] = {kvt0,  kv_b,     kv,      0, 128, 0, 0};
    p.tiles[6] = {kvt1,  kv_b+64,  kv+64,   0, 128, 0, 0};
    mgemm<<<dim3(7, 784), 256, 0, stream>>>(p);
  }
  attn_kernel<<<512, 256, 0, stream>>>(qbuf, kv, part);
  merge_kernel<<<49, 64, 0, stream>>>(part, gsm);
  // G2: xen -> t (in-place; all 128 A-rows staged to LDS before writes)
  {
    MGemmParams p; p.A = xen; p.scale = 0; p.lda = 64; p.K = 64; p.rowsPerB = HW;
    p.tiles[0] = {la2t, la2_b, xen, 0, 64, 0, 0};
    mgemm<<<dim3(1, 784), 256, 0, stream>>>(p);
  }
  dwconv_codi_kernel<<<8*28*14, 256, 0, stream>>>(rgb, xen, lac1_w, lac1_b, lac2_w, lac2_b, codi);
  dwconv128_kernel<<<8*56*14, 256, 0, stream>>>(rr2a, conv_w, conv_b, convout);
  // G3: (convout@rr3 + b) * rr1 -> xc cols 0..127
  {
    MGemmParams p; p.A = convout; p.scale = 0; p.lda = 128; p.K = 128; p.rowsPerB = HW;
    p.tiles[0] = {rr3t0, rr3_b,    xc,    rr1,    256, 128, 0};
    p.tiles[1] = {rr3t1, rr3_b+64, xc+64, rr1+64, 256, 128, 0};
    mgemm<<<dim3(2, 784), 256, 0, stream>>>(p);
  }
  reduce_kernel<<<392, 256, 0, stream>>>(codi, dotb, n1sq, n2sq);
  attc_kernel<<<1, 256, 0, stream>>>(dotb, n1sq, n2sq, fc1_w, fc2_w, attc);
  // G4: (codi * attc) @ la3 -> xc cols 192..255
  {
    MGemmParams p; p.A = codi; p.scale = attc; p.lda = 128; p.K = 128; p.rowsPerB = HW;
    p.tiles[0] = {la3t, la3_b, xc + 192, 0, 256, 0, 0};
    mgemm<<<dim3(1, 784), 256, 0, stream>>>(p);
  }
  f2_kernel<<<25088, 256, 0, stream>>>(gsm, xc);
  // G5: xc -> out | out_e (fp32 outputs)
  {
    MGemmParams p; p.A = xc; p.scale = 0; p.lda = 256; p.K = 256; p.rowsPerB = HW;
    p.tiles[0] = {projt0, proj_b,    outp,    0, 128, 0, 1};
    p.tiles[1] = {projt1, proj_b+64, outp+64, 0, 128, 0, 1};
    p.tiles[2] = {projet, proje_b,   oute,    0,  64, 0, 1};
    mgemm<<<dim3(3, 784), 256, 0, stream>>>(p);
  }
}

// Round 6
// 649.930 us; speedup vs baseline: 2.6398x; 1.2760x over previous
//
#include <hip/hip_runtime.h>
#include <math.h>

#define N_POS 100352   // 8*112*112
#define HW    12544    // 112*112

typedef unsigned short bf16_t;
typedef __attribute__((ext_vector_type(8))) short bf16x8;
typedef __attribute__((ext_vector_type(4))) float f32x4;

__device__ __forceinline__ bf16_t f2b(float f){
  unsigned u = __builtin_bit_cast(unsigned, f);
  unsigned r = (u + 0x7fffu + ((u >> 16) & 1u)) >> 16;
  return (bf16_t)r;
}
__device__ __forceinline__ float b2f(bf16_t h){
  unsigned u = ((unsigned)h) << 16;
  return __builtin_bit_cast(float, u);
}
__device__ __forceinline__ float blo(unsigned u){
  return __builtin_bit_cast(float, u << 16);
}
__device__ __forceinline__ float bhi(unsigned u){
  return __builtin_bit_cast(float, u & 0xffff0000u);
}

// ---------------- zero ----------------
__global__ void zero_kernel(float* p, int n){
  int i = blockIdx.x*256 + threadIdx.x;
  if (i < n) p[i] = 0.f;
}

// ---------------- weight transpose+cast: Wt[n][k] = bf16(W[k][n0+n]) ----------------
struct WJob { const float* src; bf16_t* dst; int K; int ldw; int n0; };
struct WJobs { WJob j[14]; };
__global__ void wtrans_kernel(WJobs js){
  WJob job = js.j[blockIdx.x];
  int t = threadIdx.x;
  int n = t & 63, k0 = t >> 6;
  for (int k = k0; k < job.K; k += 4)
    job.dst[(size_t)n*job.K + k] = f2b(job.src[(size_t)k*job.ldw + job.n0 + n]);
}

// ---------------- LayerNorm (128 ch) -> bf16 ----------------
__global__ __launch_bounds__(256) void ln128_kernel(const float* __restrict__ in,
    const float* __restrict__ w, const float* __restrict__ b, bf16_t* __restrict__ out){
  int row  = blockIdx.x*4 + (threadIdx.x >> 6);
  int lane = threadIdx.x & 63;
  const float* p = in + (size_t)row*128;
  float2 v = *(const float2*)(p + lane*2);
  float s = v.x + v.y;
  #pragma unroll
  for (int o = 1; o < 64; o <<= 1) s += __shfl_xor(s, o);
  float mu = s * (1.0f/128.0f);
  float dx = v.x - mu, dy = v.y - mu;
  float q = dx*dx + dy*dy;
  #pragma unroll
  for (int o = 1; o < 64; o <<= 1) q += __shfl_xor(q, o);
  float rs = rsqrtf(q * (1.0f/128.0f) + 1e-6f);
  int c = lane*2;
  ushort2 o2;
  o2.x = f2b(dx*rs*w[c]   + b[c]);
  o2.y = f2b(dy*rs*w[c+1] + b[c+1]);
  *(ushort2*)(out + (size_t)row*128 + c) = o2;
}

// ---------------- LayerNorm (64 ch) -> bf16 ----------------
__global__ __launch_bounds__(256) void ln64_kernel(const float* __restrict__ in,
    const float* __restrict__ w, const float* __restrict__ b, bf16_t* __restrict__ out){
  int row  = blockIdx.x*4 + (threadIdx.x >> 6);
  int lane = threadIdx.x & 63;
  float v = in[(size_t)row*64 + lane];
  float s = v;
  #pragma unroll
  for (int o = 1; o < 64; o <<= 1) s += __shfl_xor(s, o);
  float mu = s * (1.0f/64.0f);
  float d = v - mu;
  float q = d*d;
  #pragma unroll
  for (int o = 1; o < 64; o <<= 1) q += __shfl_xor(q, o);
  float rs = rsqrtf(q * (1.0f/64.0f) + 1e-6f);
  out[(size_t)row*64 + lane] = f2b(d*rs*w[lane] + b[lane]);
}

// ---------------- bf16 MFMA GEMM: 128x64 block, 4 waves x (32x64) ----------------
struct MTile {
  const bf16_t* Wt;    // [64][K] pre-transposed bf16
  const float* bias;
  void* out;           // bf16 or fp32 (out_fp32)
  const bf16_t* mult;  // optional gate, bf16 [row][ldm]
  int ldo; int ldm; int out_fp32;
};
struct MGemmParams {
  const bf16_t* A; const float* scale;
  int lda; int K; int rowsPerB;
  MTile tiles[8];
};

__global__ __launch_bounds__(256) void mgemm(MGemmParams p){
  __shared__ short As[128*72];
  __shared__ short Ws[64*72];
  const int tid = threadIdx.x;
  const MTile tile = p.tiles[blockIdx.x];
  const int row0 = blockIdx.y * 128;
  const int lane = tid & 63, wv = tid >> 6;
  const int wm = wv * 32;
  const int fm = lane & 15;
  const int quad = lane >> 4;
  f32x4 acc[2][4];
  #pragma unroll
  for (int mi = 0; mi < 2; mi++)
    #pragma unroll
    for (int ni = 0; ni < 4; ni++) acc[mi][ni] = (f32x4)0.f;
  const float* scale = p.scale ? (p.scale + (size_t)(row0 / p.rowsPerB) * p.K) : (const float*)0;

  const int sr = tid & 127, sq = tid >> 7;
  const int wn = tid & 63,  wq = tid >> 6;

  for (int k0 = 0; k0 < p.K; k0 += 64) {
    {
      const bf16_t* src = p.A + (size_t)(row0 + sr)*p.lda + k0 + sq*32;
      short* dst = &As[sr*72 + sq*32];
      if (!scale) {
        #pragma unroll
        for (int i = 0; i < 4; i++)
          *(uint4*)(dst + i*8) = *(const uint4*)(src + i*8);
      } else {
        const float* sc = scale + k0 + sq*32;
        #pragma unroll
        for (int i = 0; i < 32; i++) dst[i] = (short)f2b(b2f(src[i]) * sc[i]);
      }
    }
    {
      const bf16_t* src = tile.Wt + (size_t)wn*p.K + k0 + wq*16;
      short* dst = &Ws[wn*72 + wq*16];
      *(uint4*)dst       = *(const uint4*)src;
      *(uint4*)(dst + 8) = *(const uint4*)(src + 8);
    }
    __syncthreads();
    #pragma unroll
    for (int ks = 0; ks < 2; ks++) {
      int kb = ks*32 + quad*8;
      bf16x8 af0 = *(const bf16x8*)&As[(wm + fm)*72 + kb];
      bf16x8 af1 = *(const bf16x8*)&As[(wm + 16 + fm)*72 + kb];
      bf16x8 bfr[4];
      #pragma unroll
      for (int ni = 0; ni < 4; ni++) bfr[ni] = *(const bf16x8*)&Ws[(ni*16 + fm)*72 + kb];
      #pragma unroll
      for (int ni = 0; ni < 4; ni++) {
        acc[0][ni] = __builtin_amdgcn_mfma_f32_16x16x32_bf16(af0, bfr[ni], acc[0][ni], 0, 0, 0);
        acc[1][ni] = __builtin_amdgcn_mfma_f32_16x16x32_bf16(af1, bfr[ni], acc[1][ni], 0, 0, 0);
      }
    }
    __syncthreads();
  }
  #pragma unroll
  for (int mi = 0; mi < 2; mi++) {
    #pragma unroll
    for (int ni = 0; ni < 4; ni++) {
      int col = ni*16 + fm;
      float bias = tile.bias[col];
      #pragma unroll
      for (int r = 0; r < 4; r++) {
        int row = row0 + wm + mi*16 + quad*4 + r;
        float val = acc[mi][ni][r] + bias;
        if (tile.mult) val *= b2f(tile.mult[(size_t)row*tile.ldm + col]);
        if (tile.out_fp32) ((float*)tile.out)[(size_t)row*tile.ldo + col] = val;
        else ((bf16_t*)tile.out)[(size_t)row*tile.ldo + col] = f2b(val);
      }
    }
  }
}

// ---------------- 7x7 depthwise conv, 128 ch ----------------
// lane owns a channel PAIR (dword loads); thread computes 8x * 2y outputs.
// Weights staged transposed [k][ch] so pair fetch is one float2.
__global__ __launch_bounds__(256) void dwconv128_kernel(const bf16_t* __restrict__ in,
    const float* __restrict__ cw, const float* __restrict__ cb, bf16_t* __restrict__ out){
  __shared__ float wsm[49*128];
  int t = threadIdx.x;
  for (int i = t; i < 6272; i += 256) {
    int ch = i / 49, k = i % 49;
    wsm[k*128 + ch] = cw[i];
  }
  __syncthreads();
  int c = (t & 63) * 2;               // channel pair base
  int wv = t >> 6;                    // 0..3 -> y pair
  int blk = blockIdx.x;               // 8 * 14 * 14
  int xs = blk % 14; int tmp = blk / 14;
  int yg = tmp % 14; int b = tmp / 14;
  int y0 = yg*8 + wv*2;               // outputs y0, y0+1
  int x0 = xs*8;
  float2 bias; bias.x = cb[c]; bias.y = cb[c+1];
  float2 acc0[8], acc1[8];
  #pragma unroll
  for (int i = 0; i < 8; i++) { acc0[i] = bias; acc1[i] = bias; }
  for (int r = 0; r < 8; r++) {
    int yy = y0 + r - 3;
    if ((unsigned)yy >= 112u) continue;          // wave-uniform
    const bf16_t* row = in + ((size_t)(b*112+yy)*112)*128 + c;
    unsigned u[14];
    #pragma unroll
    for (int i = 0; i < 14; i++) {
      int xx = x0 + i - 3;
      u[i] = ((unsigned)xx < 112u) ? *(const unsigned*)(row + (size_t)xx*128) : 0u;
    }
    float va[14], vb[14];
    #pragma unroll
    for (int i = 0; i < 14; i++) { va[i] = blo(u[i]); vb[i] = bhi(u[i]); }
    if (r < 7) {                                  // yout = y0, ky = r
      #pragma unroll
      for (int kx = 0; kx < 7; kx++) {
        float2 w = *(const float2*)&wsm[(r*7+kx)*128 + c];
        #pragma unroll
        for (int i = 0; i < 8; i++) {
          acc0[i].x = fmaf(w.x, va[i+kx], acc0[i].x);
          acc0[i].y = fmaf(w.y, vb[i+kx], acc0[i].y);
        }
      }
    }
    if (r >= 1) {                                 // yout = y0+1, ky = r-1
      #pragma unroll
      for (int kx = 0; kx < 7; kx++) {
        float2 w = *(const float2*)&wsm[((r-1)*7+kx)*128 + c];
        #pragma unroll
        for (int i = 0; i < 8; i++) {
          acc1[i].x = fmaf(w.x, va[i+kx], acc1[i].x);
          acc1[i].y = fmaf(w.y, vb[i+kx], acc1[i].y);
        }
      }
    }
  }
  size_t r0 = (size_t)(b*112+y0)*112 + x0;
  #pragma unroll
  for (int i = 0; i < 8; i++) {
    unsigned o0 = (unsigned)f2b(acc0[i].x) | ((unsigned)f2b(acc0[i].y) << 16);
    unsigned o1 = (unsigned)f2b(acc1[i].x) | ((unsigned)f2b(acc1[i].y) << 16);
    *(unsigned*)(out + (r0+i)*128 + c)       = o0;
    *(unsigned*)(out + (r0+112+i)*128 + c)   = o1;
  }
}

// ---------------- co/di fused dwconv, channel-paired ----------------
__global__ __launch_bounds__(256) void dwconv_codi_kernel(
    const bf16_t* __restrict__ rgb, const bf16_t* __restrict__ tb,
    const float* __restrict__ w1, const float* __restrict__ b1,
    const float* __restrict__ w2, const float* __restrict__ b2,
    bf16_t* __restrict__ out){
  __shared__ float wsm[49*128];   // [k][co 64 | di 64]
  int t = threadIdx.x;
  for (int i = t; i < 3136; i += 256) {
    int ch = i / 49, k = i % 49;
    wsm[k*128 + ch]      = w1[i];
    wsm[k*128 + 64 + ch] = w2[i];
  }
  __syncthreads();
  int c = (t & 31) * 2;               // channel pair (of 64)
  int yrow = t >> 5;                  // 0..7
  int blk = blockIdx.x;               // 8 * 14 * 14
  int xs = blk % 14; int tmp = blk / 14;
  int yg = tmp % 14; int b = tmp / 14;
  int y = yg*8 + yrow;
  int x0 = xs*8;
  float2 bco; bco.x = b1[c]; bco.y = b1[c+1];
  float2 bdi; bdi.x = b2[c]; bdi.y = b2[c+1];
  float2 acc_co[8], acc_di[8];
  #pragma unroll
  for (int i = 0; i < 8; i++) { acc_co[i] = bco; acc_di[i] = bdi; }
  for (int r = 0; r < 7; r++) {
    int yy = y + r - 3;
    if ((unsigned)yy >= 112u) continue;          // half-wave divergent at edges only
    const bf16_t* rrow = rgb + ((size_t)(b*112+yy)*112)*64 + c;
    const bf16_t* trow = tb  + ((size_t)(b*112+yy)*112)*64 + c;
    unsigned ru[14], tu[14];
    #pragma unroll
    for (int i = 0; i < 14; i++) {
      int xx = x0 + i - 3;
      bool ok = (unsigned)xx < 112u;
      ru[i] = ok ? *(const unsigned*)(rrow + (size_t)xx*64) : 0u;
      tu[i] = ok ? *(const unsigned*)(trow + (size_t)xx*64) : 0u;
    }
    float p0[14], p1[14], d0[14], d1[14];
    #pragma unroll
    for (int i = 0; i < 14; i++) {
      float a0 = blo(ru[i]), a1 = bhi(ru[i]);
      float t0 = blo(tu[i]), t1 = bhi(tu[i]);
      p0[i] = a0*t0; p1[i] = a1*t1;
      d0[i] = fabsf(a0-t0); d1[i] = fabsf(a1-t1);
    }
    #pragma unroll
    for (int kx = 0; kx < 7; kx++) {
      int k = r*7+kx;
      float2 wc = *(const float2*)&wsm[k*128 + c];
      float2 wd = *(const float2*)&wsm[k*128 + 64 + c];
      #pragma unroll
      for (int i = 0; i < 8; i++) {
        acc_co[i].x = fmaf(wc.x, p0[i+kx], acc_co[i].x);
        acc_co[i].y = fmaf(wc.y, p1[i+kx], acc_co[i].y);
        acc_di[i].x = fmaf(wd.x, d0[i+kx], acc_di[i].x);
        acc_di[i].y = fmaf(wd.y, d1[i+kx], acc_di[i].y);
      }
    }
  }
  size_t r0 = (size_t)(b*112+y)*112 + x0;
  #pragma unroll
  for (int i = 0; i < 8; i++) {
    unsigned oc = (unsigned)f2b(acc_co[i].x) | ((unsigned)f2b(acc_co[i].y) << 16);
    unsigned od = (unsigned)f2b(acc_di[i].x) | ((unsigned)f2b(acc_di[i].y) << 16);
    *(unsigned*)(out + (r0+i)*128 + c)      = oc;
    *(unsigned*)(out + (r0+i)*128 + 64 + c) = od;
  }
}

// ---------------- cosine-gate reductions (codi bf16) ----------------
__global__ __launch_bounds__(256) void reduce_kernel(const bf16_t* __restrict__ codi,
    float* __restrict__ dotb, float* __restrict__ n1sq, float* __restrict__ n2sq){
  int blk = blockIdx.x;          // 392
  int b = blk / 49, seg = blk % 49;
  int lane = threadIdx.x & 63, w = threadIdx.x >> 6;
  int c = lane*2;
  float d0=0,d1=0,s0=0,s1=0,a1=0;
  for (int i = 0; i < 64; i++) {
    int row = b*HW + seg*256 + w*64 + i;
    ushort2 v2 = *(const ushort2*)(codi + (size_t)row*128 + c);
    float vx = b2f(v2.x), vy = b2f(v2.y);
    float rs = vx + vy;
    #pragma unroll
    for (int o = 1; o < 64; o <<= 1) rs += __shfl_xor(rs, o);
    float amap = rs * (1.0f/128.0f);
    d0 += amap*vx; d1 += amap*vy;
    s0 += vx*vx;   s1 += vy*vy;
    if (lane == 0) a1 += amap*amap;
  }
  atomicAdd(&dotb[b*128+c],   d0); atomicAdd(&dotb[b*128+c+1], d1);
  atomicAdd(&n2sq[b*128+c],   s0); atomicAdd(&n2sq[b*128+c+1], s1);
  if (lane == 0) atomicAdd(&n1sq[b], a1);
}

__global__ __launch_bounds__(256) void attc_kernel(const float* __restrict__ dotb,
    const float* __restrict__ n1sq, const float* __restrict__ n2sq,
    const float* __restrict__ fc1, const float* __restrict__ fc2, float* __restrict__ attc){
  __shared__ float scos[128];
  __shared__ float sh[16];
  int t = threadIdx.x;
  for (int b = 0; b < 8; b++) {
    if (t < 128) {
      float n1 = sqrtf(n1sq[b]);
      float n2 = sqrtf(n2sq[b*128+t]);
      scos[t] = dotb[b*128+t] / (n1*n2 + 1e-6f);
    }
    __syncthreads();
    if (t < 16) {
      float h = 0;
      for (int c = 0; c < 128; c++) h += scos[c]*fc1[c*16+t];
      sh[t] = h * 0.5f * (1.0f + erff(h*0.70710678118654752f));
    }
    __syncthreads();
    if (t < 128) {
      float a = 0;
      for (int j = 0; j < 16; j++) a += sh[j]*fc2[j*128+t];
      attc[b*128+t] = 1.0f/(1.0f + __expf(-a));
    }
    __syncthreads();
  }
}

// ---------------- pooling (16x16 mean) of [xn|xen] (bf16) ----------------
__global__ void pool_kernel(const bf16_t* __restrict__ xn, const bf16_t* __restrict__ xen,
                            float* __restrict__ pool){
  int cellb = blockIdx.x;
  int py = blockIdx.y;
  int c = threadIdx.x;           // 0..191
  int b = cellb / 49, cell = cellb % 49;
  int wy = cell / 7, wx = cell % 7;
  float s = 0;
  for (int i = py*2; i < py*2+2; i++)
    for (int j = 0; j < 16; j++) {
      int y = wy*16+i, x = wx*16+j;
      size_t row = (size_t)(b*112+y)*112 + x;
      s += (c < 128) ? b2f(xn[row*128 + c]) : b2f(xen[row*64 + (c-128)]);
    }
  atomicAdd(&pool[(size_t)cellb*192 + c], s);
}

// ---------------- q projection ----------------
__global__ void qproj_kernel(const float* __restrict__ pool, const float* __restrict__ qw,
                             const float* __restrict__ qb, float* __restrict__ qbuf){
  int cellb = blockIdx.x;
  int j = threadIdx.x;
  float s = qb[j];
  for (int c = 0; c < 192; c++)
    s += pool[(size_t)cellb*192 + c] * (1.0f/256.0f) * qw[c*64 + j];
  qbuf[(size_t)cellb*64 + j] = s * 0.35355339059327373f;
}

// ---------------- flash attention split-K (kv bf16) ----------------
__global__ __launch_bounds__(256) void attn_kernel(const float* __restrict__ qbuf,
    const bf16_t* __restrict__ kv, float* __restrict__ part){
  __shared__ float qs[392];
  __shared__ float ks[256*8];
  __shared__ float vs[256*8];
  int t = threadIdx.x;
  int blk = blockIdx.x;
  int b = blk >> 6, nh = (blk >> 3) & 7, sp = blk & 7;
  for (int i = t; i < 392; i += 256)
    qs[i] = qbuf[(size_t)(b*49 + (i>>3))*64 + nh*8 + (i&7)];
  __syncthreads();
  int lane = t & 63, w = t >> 6;
  int qq = lane < 49 ? lane : 0;
  float4 qa = *(const float4*)&qs[qq*8];
  float4 qb4 = *(const float4*)&qs[qq*8+4];
  float m = -1e30f, l = 0.f;
  float4 acca = make_float4(0,0,0,0), accb = make_float4(0,0,0,0);
  const int base = sp * 1568;
  for (int c0 = 0; c0 < 1568; c0 += 256) {
    int cnt = 1568 - c0 < 256 ? 1568 - c0 : 256;
    __syncthreads();
    if (t < cnt) {
      size_t rb = ((size_t)(b*HW + base + c0 + t))*128 + nh*8;
      uint4 kr = *(const uint4*)(kv + rb);
      uint4 vr = *(const uint4*)(kv + rb + 64);
      const bf16_t* kp = (const bf16_t*)&kr;
      const bf16_t* vp = (const bf16_t*)&vr;
      #pragma unroll
      for (int j = 0; j < 8; j++) { ks[t*8+j] = b2f(kp[j]); vs[t*8+j] = b2f(vp[j]); }
    }
    __syncthreads();
    int s0 = w*64;
    int n = cnt - s0; if (n > 64) n = 64;
    for (int i = 0; i < n; i++) {
      const float* kp = &ks[(s0+i)*8];
      float4 ka = *(const float4*)kp, kb = *(const float4*)(kp+4);
      float s = qa.x*ka.x + qa.y*ka.y + qa.z*ka.z + qa.w*ka.w
              + qb4.x*kb.x + qb4.y*kb.y + qb4.z*kb.z + qb4.w*kb.w;
      float mn = fmaxf(m, s);
      float corr = __expf(m - mn);
      float pe   = __expf(s - mn);
      l = l*corr + pe;
      const float* vp = &vs[(s0+i)*8];
      float4 va = *(const float4*)vp, vb = *(const float4*)(vp+4);
      acca.x = acca.x*corr + pe*va.x; acca.y = acca.y*corr + pe*va.y;
      acca.z = acca.z*corr + pe*va.z; acca.w = acca.w*corr + pe*va.w;
      accb.x = accb.x*corr + pe*vb.x; accb.y = accb.y*corr + pe*vb.y;
      accb.z = accb.z*corr + pe*vb.z; accb.w = accb.w*corr + pe*vb.w;
      m = mn;
    }
  }
  if (lane < 49) {
    size_t idx = ((size_t)(blk*4 + w)*49 + lane)*10;
    part[idx] = m; part[idx+1] = l;
    part[idx+2] = acca.x; part[idx+3] = acca.y; part[idx+4] = acca.z; part[idx+5] = acca.w;
    part[idx+6] = accb.x; part[idx+7] = accb.y; part[idx+8] = accb.z; part[idx+9] = accb.w;
  }
}

__global__ void merge_kernel(const float* __restrict__ part, float* __restrict__ gsm){
  int g = blockIdx.x*64 + threadIdx.x;   // 3136
  if (g >= 3136) return;
  int b = g / 392, r = g % 392, nh = r / 49, q = r % 49;
  int blkbase = b*64 + nh*8;
  float M = -1e30f;
  for (int sp = 0; sp < 8; sp++)
    for (int w = 0; w < 4; w++) {
      size_t idx = ((size_t)((blkbase+sp)*4 + w)*49 + q)*10;
      M = fmaxf(M, part[idx]);
    }
  float L = 0, a[8] = {0,0,0,0,0,0,0,0};
  for (int sp = 0; sp < 8; sp++)
    for (int w = 0; w < 4; w++) {
      size_t idx = ((size_t)((blkbase+sp)*4 + w)*49 + q)*10;
      float c = __expf(part[idx] - M);
      L += part[idx+1]*c;
      #pragma unroll
      for (int d = 0; d < 8; d++) a[d] += part[idx+2+d]*c;
    }
  #pragma unroll
  for (int d = 0; d < 8; d++)
    gsm[(size_t)(b*49+q)*64 + nh*8 + d] = a[d]/L;
}

// ---------------- xc cols 128..191: bilinear(g) -> bf16 ----------------
__global__ __launch_bounds__(256) void f2_kernel(const float* __restrict__ gsm,
                                                 bf16_t* __restrict__ xc){
  int gidx = blockIdx.x*256 + threadIdx.x;   // N*64 total
  int r = gidx >> 6, cc = gidx & 63;
  int b = r / HW, rem = r % HW, y = rem / 112, x = rem % 112;
  float fy = fminf(fmaxf((y + 0.5f)*0.0625f - 0.5f, 0.f), 6.f);
  float fx = fminf(fmaxf((x + 0.5f)*0.0625f - 0.5f, 0.f), 6.f);
  int y0 = (int)fy, x0 = (int)fx;
  float wy = fy - y0, wx = fx - x0;
  int y1 = y0+1 < 6 ? y0+1 : 6, x1 = x0+1 < 6 ? x0+1 : 6;
  const float* gb = gsm + (size_t)b*49*64 + cc;
  float g00 = gb[(y0*7+x0)*64], g01 = gb[(y0*7+x1)*64];
  float g10 = gb[(y1*7+x0)*64], g11 = gb[(y1*7+x1)*64];
  xc[(size_t)r*256 + 128 + cc] =
      f2b((1-wy)*((1-wx)*g00 + wx*g01) + wy*((1-wx)*g10 + wx*g11));
}

// =====================================================================
extern "C" void kernel_launch(void* const* d_in, const int* in_sizes, int n_in,
                              void* d_out, int out_size, void* d_ws, size_t ws_size,
                              hipStream_t stream) {
  const float* x      = (const float*)d_in[0];
  const float* x_e    = (const float*)d_in[1];
  const float* norm_w = (const float*)d_in[2];
  const float* norm_b = (const float*)d_in[3];
  const float* norme_w= (const float*)d_in[4];
  const float* norme_b= (const float*)d_in[5];
  const float* rr1_w  = (const float*)d_in[6];
  const float* rr1_b  = (const float*)d_in[7];
  const float* rr2_w  = (const float*)d_in[8];
  const float* rr2_b  = (const float*)d_in[9];
  const float* rr3_w  = (const float*)d_in[10];
  const float* rr3_b  = (const float*)d_in[11];
  const float* conv_w = (const float*)d_in[12];
  const float* conv_b = (const float*)d_in[13];
  const float* la1_w  = (const float*)d_in[14];
  const float* la1_b  = (const float*)d_in[15];
  const float* la2_w  = (const float*)d_in[16];
  const float* la2_b  = (const float*)d_in[17];
  const float* lac1_w = (const float*)d_in[18];
  const float* lac1_b = (const float*)d_in[19];
  const float* lac2_w = (const float*)d_in[20];
  const float* lac2_b = (const float*)d_in[21];
  const float* fc1_w  = (const float*)d_in[22];
  const float* fc2_w  = (const float*)d_in[23];
  const float* la3_w  = (const float*)d_in[24];
  const float* la3_b  = (const float*)d_in[25];
  const float* kv_w   = (const float*)d_in[26];
  const float* kv_b   = (const float*)d_in[27];
  const float* q_w    = (const float*)d_in[28];
  const float* q_b    = (const float*)d_in[29];
  const float* proj_w = (const float*)d_in[30];
  const float* proj_b = (const float*)d_in[31];
  const float* proje_w= (const float*)d_in[32];
  const float* proje_b= (const float*)d_in[33];

  const size_t N = N_POS;
  bf16_t* rr1   = (bf16_t*)d_ws;     // N*128 bf16, dead after G3
  bf16_t* xnbuf = rr1 + N*128;       // N*128: xn -> convout
  bf16_t* kvbuf = xnbuf + N*128;     // N*128: kv -> codi
  bf16_t* xcbuf = kvbuf + N*128;     // N*256: [rr2a | rgb | xen/t] -> xc
  float* pool = (float*)(xcbuf + N*256);  // 75264
  float* qbuf = pool + 75264;        // 25088
  float* part = qbuf + 25088;        // 1003520
  float* gsm  = part + 1003520;      // 25088
  float* dotb = gsm  + 25088;        // 1024
  float* n1sq = dotb + 1024;         // 8
  float* n2sq = n1sq + 8;            // 1024
  float* attc = n2sq + 1024;         // 1024
  bf16_t* wtab = (bf16_t*)(attc + 1024);  // 135168 shorts

  bf16_t* xn = xnbuf;
  bf16_t* convout = xnbuf;
  bf16_t* kv = kvbuf;
  bf16_t* codi = kvbuf;
  bf16_t* rr2a = xcbuf;
  bf16_t* rgb  = xcbuf + N*128;
  bf16_t* xen  = xcbuf + N*192;
  bf16_t* xc   = xcbuf;
  float* outp = (float*)d_out;
  float* oute = outp + N*128;

  bf16_t* rr1t0 = wtab;            bf16_t* rr1t1 = wtab + 8192;
  bf16_t* rr2t0 = wtab + 16384;    bf16_t* rr2t1 = wtab + 24576;
  bf16_t* la1t  = wtab + 32768;
  bf16_t* kvt0  = wtab + 40960;    bf16_t* kvt1  = wtab + 49152;
  bf16_t* la2t  = wtab + 57344;
  bf16_t* rr3t0 = wtab + 61440;    bf16_t* rr3t1 = wtab + 69632;
  bf16_t* la3t  = wtab + 77824;
  bf16_t* projt0= wtab + 86016;    bf16_t* projt1= wtab + 102400;
  bf16_t* projet= wtab + 118784;

  zero_kernel<<<(75264+255)/256, 256, 0, stream>>>(pool, 75264);
  zero_kernel<<<9, 256, 0, stream>>>(dotb, 2056);
  {
    WJobs js;
    js.j[0]  = {rr1_w,  rr1t0, 128, 128,   0};
    js.j[1]  = {rr1_w,  rr1t1, 128, 128,  64};
    js.j[2]  = {rr2_w,  rr2t0, 128, 128,   0};
    js.j[3]  = {rr2_w,  rr2t1, 128, 128,  64};
    js.j[4]  = {la1_w,  la1t,  128,  64,   0};
    js.j[5]  = {kv_w,   kvt0,  128, 128,   0};
    js.j[6]  = {kv_w,   kvt1,  128, 128,  64};
    js.j[7]  = {la2_w,  la2t,   64,  64,   0};
    js.j[8]  = {rr3_w,  rr3t0, 128, 128,   0};
    js.j[9]  = {rr3_w,  rr3t1, 128, 128,  64};
    js.j[10] = {la3_w,  la3t,  128,  64,   0};
    js.j[11] = {proj_w, projt0,256, 128,   0};
    js.j[12] = {proj_w, projt1,256, 128,  64};
    js.j[13] = {proje_w,projet,256,  64,   0};
    wtrans_kernel<<<14, 256, 0, stream>>>(js);
  }
  ln128_kernel<<<N_POS/4, 256, 0, stream>>>(x, norm_w, norm_b, xn);
  ln64_kernel <<<N_POS/4, 256, 0, stream>>>(x_e, norme_w, norme_b, xen);
  pool_kernel<<<dim3(392,8), 192, 0, stream>>>(xn, xen, pool);
  qproj_kernel<<<392, 64, 0, stream>>>(pool, q_w, q_b, qbuf);
  // G1: xn -> rr1 | rr2a | rgb | kv
  {
    MGemmParams p; p.A = xn; p.scale = 0; p.lda = 128; p.K = 128; p.rowsPerB = HW;
    p.tiles[0] = {rr1t0, rr1_b,    rr1,     0, 128, 0, 0};
    p.tiles[1] = {rr1t1, rr1_b+64, rr1+64,  0, 128, 0, 0};
    p.tiles[2] = {rr2t0, rr2_b,    rr2a,    0, 128, 0, 0};
    p.tiles[3] = {rr2t1, rr2_b+64, rr2a+64, 0, 128, 0, 0};
    p.tiles[4] = {la1t,  la1_b,    rgb,     0,  64, 0, 0};
    p.tiles[5] = {kvt0,  kv_b,     kv,      0, 128, 0, 0};
    p.tiles[6] = {kvt1,  kv_b+64,  kv+64,   0, 128, 0, 0};
    mgemm<<<dim3(7, 784), 256, 0, stream>>>(p);
  }
  attn_kernel<<<512, 256, 0, stream>>>(qbuf, kv, part);
  merge_kernel<<<49, 64, 0, stream>>>(part, gsm);
  // G2: xen -> t (in-place)
  {
    MGemmParams p; p.A = xen; p.scale = 0; p.lda = 64; p.K = 64; p.rowsPerB = HW;
    p.tiles[0] = {la2t, la2_b, xen, 0, 64, 0, 0};
    mgemm<<<dim3(1, 784), 256, 0, stream>>>(p);
  }
  dwconv_codi_kernel<<<8*14*14, 256, 0, stream>>>(rgb, xen, lac1_w, lac1_b, lac2_w, lac2_b, codi);
  dwconv128_kernel<<<8*14*14, 256, 0, stream>>>(rr2a, conv_w, conv_b, convout);
  // G3: (convout@rr3 + b) * rr1 -> xc cols 0..127
  {
    MGemmParams p; p.A = convout; p.scale = 0; p.lda = 128; p.K = 128; p.rowsPerB = HW;
    p.tiles[0] = {rr3t0, rr3_b,    xc,    rr1,    256, 128, 0};
    p.tiles[1] = {rr3t1, rr3_b+64, xc+64, rr1+64, 256, 128, 0};
    mgemm<<<dim3(2, 784), 256, 0, stream>>>(p);
  }
  reduce_kernel<<<392, 256, 0, stream>>>(codi, dotb, n1sq, n2sq);
  attc_kernel<<<1, 256, 0, stream>>>(dotb, n1sq, n2sq, fc1_w, fc2_w, attc);
  // G4: (codi * attc) @ la3 -> xc cols 192..255
  {
    MGemmParams p; p.A = codi; p.scale = attc; p.lda = 128; p.K = 128; p.rowsPerB = HW;
    p.tiles[0] = {la3t, la3_b, xc + 192, 0, 256, 0, 0};
    mgemm<<<dim3(1, 784), 256, 0, stream>>>(p);
  }
  f2_kernel<<<25088, 256, 0, stream>>>(gsm, xc);
  // G5: xc -> out | out_e (fp32 outputs)
  {
    MGemmParams p; p.A = xc; p.scale = 0; p.lda = 256; p.K = 256; p.rowsPerB = HW;
    p.tiles[0] = {projt0, proj_b,    outp,    0, 128, 0, 1};
    p.tiles[1] = {projt1, proj_b+64, outp+64, 0, 128, 0, 1};
    p.tiles[2] = {projet, proje_b,   oute,    0,  64, 0, 1};
    mgemm<<<dim3(3, 784), 256, 0, stream>>>(p);
  }
}